// Round 1
// baseline (2006.293 us; speedup 1.0000x reference)
//
#include <hip/hip_runtime.h>
#include <math.h>

#define N_TOK 4096
#define DIM   768
#define NH    12
#define HD    64

// ---------------------------------------------------------------------------
// fp32 GEMM: C[M x N] = A[M x K] * B[K x N] + bias[N]
// 128x128 block tile, BK=16, 256 threads, 8x8 per thread (split 4+4 for LDS
// bank spread). M,N divisible by 128; K divisible by 16.
// ---------------------------------------------------------------------------
template<int M, int N, int K>
__global__ __launch_bounds__(256)
void gemm_bias(const float* __restrict__ A, const float* __restrict__ B,
               const float* __restrict__ bias, float* __restrict__ C) {
    __shared__ float As[16][128];   // transposed A tile: As[k][m]
    __shared__ float Bs[16][128];
    const int t  = threadIdx.x;
    const int tx = t & 15, ty = t >> 4;
    const int m0 = blockIdx.y * 128, n0 = blockIdx.x * 128;

    float acc[8][8];
#pragma unroll
    for (int i = 0; i < 8; ++i)
#pragma unroll
        for (int j = 0; j < 8; ++j) acc[i][j] = 0.f;

    for (int k0 = 0; k0 < K; k0 += 16) {
        // A tile 128x16 -> As (transposed)
#pragma unroll
        for (int u = 0; u < 2; ++u) {
            int idx = u * 256 + t;          // 0..511
            int row = idx >> 2;             // 0..127
            int c4  = idx & 3;              // 0..3
            float4 v = *(const float4*)&A[(size_t)(m0 + row) * K + k0 + c4 * 4];
            As[c4 * 4 + 0][row] = v.x;
            As[c4 * 4 + 1][row] = v.y;
            As[c4 * 4 + 2][row] = v.z;
            As[c4 * 4 + 3][row] = v.w;
        }
        // B tile 16x128 -> Bs
#pragma unroll
        for (int u = 0; u < 2; ++u) {
            int idx = u * 256 + t;
            int row = idx >> 5;             // 0..15
            int c4  = idx & 31;             // 0..31
            *(float4*)&Bs[row][c4 * 4] =
                *(const float4*)&B[(size_t)(k0 + row) * N + n0 + c4 * 4];
        }
        __syncthreads();
#pragma unroll
        for (int kk = 0; kk < 16; ++kk) {
            float4 a0 = *(float4*)&As[kk][ty * 4];
            float4 a1 = *(float4*)&As[kk][64 + ty * 4];
            float4 b0 = *(float4*)&Bs[kk][tx * 4];
            float4 b1 = *(float4*)&Bs[kk][64 + tx * 4];
            float av[8] = {a0.x, a0.y, a0.z, a0.w, a1.x, a1.y, a1.z, a1.w};
            float bv[8] = {b0.x, b0.y, b0.z, b0.w, b1.x, b1.y, b1.z, b1.w};
#pragma unroll
            for (int i = 0; i < 8; ++i)
#pragma unroll
                for (int j = 0; j < 8; ++j)
                    acc[i][j] = fmaf(av[i], bv[j], acc[i][j]);
        }
        __syncthreads();
    }

    float4 bi0 = *(const float4*)&bias[n0 + tx * 4];
    float4 bi1 = *(const float4*)&bias[n0 + 64 + tx * 4];
    float bb[8] = {bi0.x, bi0.y, bi0.z, bi0.w, bi1.x, bi1.y, bi1.z, bi1.w};
#pragma unroll
    for (int i = 0; i < 8; ++i) {
        int rloc = (i < 4) ? (ty * 4 + i) : (64 + ty * 4 + (i - 4));
        size_t row = (size_t)(m0 + rloc);
        float4 o0 = make_float4(acc[i][0] + bb[0], acc[i][1] + bb[1],
                                acc[i][2] + bb[2], acc[i][3] + bb[3]);
        float4 o1 = make_float4(acc[i][4] + bb[4], acc[i][5] + bb[5],
                                acc[i][6] + bb[6], acc[i][7] + bb[7]);
        *(float4*)&C[row * N + n0 + tx * 4]      = o0;
        *(float4*)&C[row * N + n0 + 64 + tx * 4] = o1;
    }
}

// ---------------------------------------------------------------------------
// Rel-pos precompute. One block per (qh, head).
//   rh[h][q][kt] = sum_c q[q][c] * rel_pos_h[qh - kt + 63][c]   (q = qh*64+qw)
//   rw[h][q][kw] = sum_c q[q][c] * rel_pos_w[qw - kw + 63][c]
// q is the UNSCALED q from qkv.
// ---------------------------------------------------------------------------
__global__ __launch_bounds__(256)
void relpos_kernel(const float* __restrict__ qkv,
                   const float* __restrict__ rel_pos_h,
                   const float* __restrict__ rel_pos_w,
                   float* __restrict__ rh, float* __restrict__ rw) {
    const int qh = blockIdx.x;   // 0..63
    const int h  = blockIdx.y;   // 0..11
    const int t  = threadIdx.x, tx = t & 15, ty = t >> 4;

    __shared__ float Qt[64][68];
    __shared__ float RH[64][68];    // RH[kt][c] = rel_pos_h[qh-kt+63][c]
    __shared__ float RW[127][68];   // all rows of rel_pos_w

#pragma unroll
    for (int u = 0; u < 4; ++u) {
        int idx = u * 256 + t;      // 0..1023
        int row = idx >> 4, c4 = idx & 15;
        *(float4*)&Qt[row][c4 * 4] =
            *(const float4*)&qkv[(size_t)(qh * 64 + row) * (3 * DIM) + h * HD + c4 * 4];
        *(float4*)&RH[row][c4 * 4] =
            *(const float4*)&rel_pos_h[(size_t)(qh - row + 63) * HD + c4 * 4];
    }
#pragma unroll
    for (int u = 0; u < 8; ++u) {
        int idx = u * 256 + t;      // need 0..2031
        if (idx < 127 * 16) {
            int row = idx >> 4, c4 = idx & 15;
            *(float4*)&RW[row][c4 * 4] =
                *(const float4*)&rel_pos_w[(size_t)row * HD + c4 * 4];
        }
    }
    __syncthreads();

    float acc1[4][4], acc2[4][4];
#pragma unroll
    for (int i = 0; i < 4; ++i)
#pragma unroll
        for (int j = 0; j < 4; ++j) { acc1[i][j] = 0.f; acc2[i][j] = 0.f; }

    for (int c4 = 0; c4 < 16; ++c4) {
        float4 q4[4], r4[4];
#pragma unroll
        for (int i = 0; i < 4; ++i) q4[i] = *(float4*)&Qt[ty * 4 + i][c4 * 4];
#pragma unroll
        for (int j = 0; j < 4; ++j) r4[j] = *(float4*)&RH[tx * 4 + j][c4 * 4];
#pragma unroll
        for (int i = 0; i < 4; ++i)
#pragma unroll
            for (int j = 0; j < 4; ++j) {
                acc1[i][j] = fmaf(q4[i].x, r4[j].x, acc1[i][j]);
                acc1[i][j] = fmaf(q4[i].y, r4[j].y, acc1[i][j]);
                acc1[i][j] = fmaf(q4[i].z, r4[j].z, acc1[i][j]);
                acc1[i][j] = fmaf(q4[i].w, r4[j].w, acc1[i][j]);
            }
#pragma unroll
        for (int i = 0; i < 4; ++i)
#pragma unroll
            for (int j = 0; j < 4; ++j) {
                float4 w4 = *(float4*)&RW[(ty * 4 + i) - (tx * 4 + j) + 63][c4 * 4];
                acc2[i][j] = fmaf(q4[i].x, w4.x, acc2[i][j]);
                acc2[i][j] = fmaf(q4[i].y, w4.y, acc2[i][j]);
                acc2[i][j] = fmaf(q4[i].z, w4.z, acc2[i][j]);
                acc2[i][j] = fmaf(q4[i].w, w4.w, acc2[i][j]);
            }
    }
#pragma unroll
    for (int i = 0; i < 4; ++i) {
        size_t base = ((size_t)h * N_TOK + qh * 64 + ty * 4 + i) * 64 + tx * 4;
        *(float4*)&rh[base] = make_float4(acc1[i][0], acc1[i][1], acc1[i][2], acc1[i][3]);
        *(float4*)&rw[base] = make_float4(acc2[i][0], acc2[i][1], acc2[i][2], acc2[i][3]);
    }
}

// ---------------------------------------------------------------------------
// Flash attention, fp32. One block per (q-tile of 64 rows, head).
// K-tiles of 64 columns align with kh: for tile kt, rel term =
//   rh[q][kt] (const over tile cols) + rw[q][j] (const over tiles).
// ---------------------------------------------------------------------------
__global__ __launch_bounds__(256)
void attn_kernel(const float* __restrict__ qkv, const float* __restrict__ rh,
                 const float* __restrict__ rw, float* __restrict__ out) {
    const int qt = blockIdx.x;   // 0..63
    const int h  = blockIdx.y;   // 0..11
    const int t  = threadIdx.x, tx = t & 15, ty = t >> 4;
    const int rbase = ty * 4;    // this thread's 4 q-rows (local)

    __shared__ float Qs[64][68], Ks[64][68], Vs[64][68], Ps[64][68];
    __shared__ float RHs[64][64], RWs[64][68];

    // load Q (scaled), RHs, RWs
#pragma unroll
    for (int u = 0; u < 4; ++u) {
        int idx = u * 256 + t;   // 0..1023
        int row = idx >> 4, c4 = idx & 15;
        float4 qv = *(const float4*)&qkv[(size_t)(qt * 64 + row) * (3 * DIM) + h * HD + c4 * 4];
        *(float4*)&Qs[row][c4 * 4] =
            make_float4(qv.x * 0.125f, qv.y * 0.125f, qv.z * 0.125f, qv.w * 0.125f);
        size_t rbase_g = ((size_t)h * N_TOK + qt * 64 + row) * 64 + c4 * 4;
        *(float4*)&RHs[row][c4 * 4] = *(const float4*)&rh[rbase_g];
        *(float4*)&RWs[row][c4 * 4] = *(const float4*)&rw[rbase_g];
    }

    float m_r[4], l_r[4], acc[4][4];
#pragma unroll
    for (int i = 0; i < 4; ++i) {
        m_r[i] = -INFINITY; l_r[i] = 0.f;
#pragma unroll
        for (int j = 0; j < 4; ++j) acc[i][j] = 0.f;
    }

    for (int kt = 0; kt < 64; ++kt) {
        __syncthreads();   // prev PV done before overwriting Ks/Vs
#pragma unroll
        for (int u = 0; u < 4; ++u) {
            int idx = u * 256 + t;
            int row = idx >> 4, c4 = idx & 15;
            size_t base = (size_t)(kt * 64 + row) * (3 * DIM) + h * HD + c4 * 4;
            *(float4*)&Ks[row][c4 * 4] = *(const float4*)&qkv[base + DIM];
            *(float4*)&Vs[row][c4 * 4] = *(const float4*)&qkv[base + 2 * DIM];
        }
        __syncthreads();

        // S = Qs * Ks^T  (thread: rows rbase.., cols tx*4..)
        float s[4][4];
#pragma unroll
        for (int i = 0; i < 4; ++i)
#pragma unroll
            for (int j = 0; j < 4; ++j) s[i][j] = 0.f;
        for (int c4 = 0; c4 < 16; ++c4) {
            float4 q4[4], k4[4];
#pragma unroll
            for (int i = 0; i < 4; ++i) q4[i] = *(float4*)&Qs[rbase + i][c4 * 4];
#pragma unroll
            for (int j = 0; j < 4; ++j) k4[j] = *(float4*)&Ks[tx * 4 + j][c4 * 4];
#pragma unroll
            for (int i = 0; i < 4; ++i)
#pragma unroll
                for (int j = 0; j < 4; ++j) {
                    s[i][j] = fmaf(q4[i].x, k4[j].x, s[i][j]);
                    s[i][j] = fmaf(q4[i].y, k4[j].y, s[i][j]);
                    s[i][j] = fmaf(q4[i].z, k4[j].z, s[i][j]);
                    s[i][j] = fmaf(q4[i].w, k4[j].w, s[i][j]);
                }
        }
        // rel-pos terms
#pragma unroll
        for (int i = 0; i < 4; ++i) {
            float rhv = RHs[rbase + i][kt];
#pragma unroll
            for (int j = 0; j < 4; ++j)
                s[i][j] += rhv + RWs[rbase + i][tx * 4 + j];
        }
        // row max (across 16 lanes of the row group)
        float tmax[4];
#pragma unroll
        for (int i = 0; i < 4; ++i)
            tmax[i] = fmaxf(fmaxf(s[i][0], s[i][1]), fmaxf(s[i][2], s[i][3]));
#pragma unroll
        for (int off = 1; off < 16; off <<= 1)
#pragma unroll
            for (int i = 0; i < 4; ++i)
                tmax[i] = fmaxf(tmax[i], __shfl_xor(tmax[i], off, 64));

        float rsum[4];
#pragma unroll
        for (int i = 0; i < 4; ++i) {
            float mnew = fmaxf(m_r[i], tmax[i]);
            float corr = __expf(m_r[i] - mnew);
            m_r[i] = mnew;
            float su = 0.f;
#pragma unroll
            for (int j = 0; j < 4; ++j) {
                s[i][j] = __expf(s[i][j] - mnew);
                su += s[i][j];
            }
            rsum[i] = su;
            l_r[i] *= corr;
#pragma unroll
            for (int j = 0; j < 4; ++j) acc[i][j] *= corr;
        }
#pragma unroll
        for (int off = 1; off < 16; off <<= 1)
#pragma unroll
            for (int i = 0; i < 4; ++i)
                rsum[i] += __shfl_xor(rsum[i], off, 64);
#pragma unroll
        for (int i = 0; i < 4; ++i) l_r[i] += rsum[i];

        // write P
#pragma unroll
        for (int i = 0; i < 4; ++i)
            *(float4*)&Ps[rbase + i][tx * 4] =
                make_float4(s[i][0], s[i][1], s[i][2], s[i][3]);
        __syncthreads();

        // PV: acc[i][d] += sum_j P[row_i][j] * V[j][d]   (d = tx*4..)
        for (int j4 = 0; j4 < 16; ++j4) {
            float4 p4[4], v4[4];
#pragma unroll
            for (int i = 0; i < 4; ++i) p4[i] = *(float4*)&Ps[rbase + i][j4 * 4];
#pragma unroll
            for (int jj = 0; jj < 4; ++jj) v4[jj] = *(float4*)&Vs[j4 * 4 + jj][tx * 4];
#pragma unroll
            for (int i = 0; i < 4; ++i) {
                acc[i][0] = fmaf(p4[i].x, v4[0].x, acc[i][0]);
                acc[i][0] = fmaf(p4[i].y, v4[1].x, acc[i][0]);
                acc[i][0] = fmaf(p4[i].z, v4[2].x, acc[i][0]);
                acc[i][0] = fmaf(p4[i].w, v4[3].x, acc[i][0]);
                acc[i][1] = fmaf(p4[i].x, v4[0].y, acc[i][1]);
                acc[i][1] = fmaf(p4[i].y, v4[1].y, acc[i][1]);
                acc[i][1] = fmaf(p4[i].z, v4[2].y, acc[i][1]);
                acc[i][1] = fmaf(p4[i].w, v4[3].y, acc[i][1]);
                acc[i][2] = fmaf(p4[i].x, v4[0].z, acc[i][2]);
                acc[i][2] = fmaf(p4[i].y, v4[1].z, acc[i][2]);
                acc[i][2] = fmaf(p4[i].z, v4[2].z, acc[i][2]);
                acc[i][2] = fmaf(p4[i].w, v4[3].z, acc[i][2]);
                acc[i][3] = fmaf(p4[i].x, v4[0].w, acc[i][3]);
                acc[i][3] = fmaf(p4[i].y, v4[1].w, acc[i][3]);
                acc[i][3] = fmaf(p4[i].z, v4[2].w, acc[i][3]);
                acc[i][3] = fmaf(p4[i].w, v4[3].w, acc[i][3]);
            }
        }
    }

    // epilogue: out[q][h*64 + d] = acc / l
#pragma unroll
    for (int i = 0; i < 4; ++i) {
        float inv = 1.0f / l_r[i];
        float4 o = make_float4(acc[i][0] * inv, acc[i][1] * inv,
                               acc[i][2] * inv, acc[i][3] * inv);
        *(float4*)&out[(size_t)(qt * 64 + rbase + i) * DIM + h * HD + tx * 4] = o;
    }
}

// ---------------------------------------------------------------------------
extern "C" void kernel_launch(void* const* d_in, const int* in_sizes, int n_in,
                              void* d_out, int out_size, void* d_ws, size_t ws_size,
                              hipStream_t stream) {
    const float* x      = (const float*)d_in[0];  // 4096 x 768
    const float* w_qkv  = (const float*)d_in[1];  // 768 x 2304
    const float* b_qkv  = (const float*)d_in[2];  // 2304
    const float* w_proj = (const float*)d_in[3];  // 768 x 768
    const float* b_proj = (const float*)d_in[4];  // 768
    const float* rph    = (const float*)d_in[5];  // 127 x 64
    const float* rpw    = (const float*)d_in[6];  // 127 x 64
    float* out = (float*)d_out;

    float* ws  = (float*)d_ws;
    float* qkv = ws;                          // 4096*2304 = 9437184
    float* rh  = qkv + (size_t)N_TOK * 3 * DIM;   // 12*4096*64 = 3145728
    float* rw  = rh + (size_t)NH * N_TOK * 64;
    float* ao  = rw + (size_t)NH * N_TOK * 64;    // 4096*768

    // 1. qkv = x @ w_qkv + b_qkv
    gemm_bias<N_TOK, 3 * DIM, DIM><<<dim3(18, 32), 256, 0, stream>>>(x, w_qkv, b_qkv, qkv);
    // 2. rel-pos tables
    relpos_kernel<<<dim3(64, NH), 256, 0, stream>>>(qkv, rph, rpw, rh, rw);
    // 3. attention
    attn_kernel<<<dim3(64, NH), 256, 0, stream>>>(qkv, rh, rw, ao);
    // 4. out = ao @ w_proj + b_proj
    gemm_bias<N_TOK, DIM, DIM><<<dim3(6, 32), 256, 0, stream>>>(ao, w_proj, b_proj, out);
}

// Round 3
// 667.054 us; speedup vs baseline: 3.0077x; 3.0077x over previous
//
#include <hip/hip_runtime.h>
#include <math.h>

#define N_TOK 4096
#define DIM   768
#define NH    12
#define HD    64

typedef __attribute__((ext_vector_type(8))) short bf16x8;
typedef __attribute__((ext_vector_type(4))) float f32x4;
typedef __attribute__((ext_vector_type(4))) unsigned short us4;

__device__ inline unsigned short f2b(float f) {   // fp32 -> bf16 RNE
    union { float f; unsigned int u; } v; v.f = f;
    unsigned int r = v.u + 0x7FFFu + ((v.u >> 16) & 1u);
    return (unsigned short)(r >> 16);
}

// ---------------------------------------------------------------------------
// fp32 GEMM: C[M x N] = A[M x K] * B[K x N] + bias[N]   (unchanged from R1)
// ---------------------------------------------------------------------------
template<int M, int N, int K>
__global__ __launch_bounds__(256)
void gemm_bias(const float* __restrict__ A, const float* __restrict__ B,
               const float* __restrict__ bias, float* __restrict__ C) {
    __shared__ float As[16][128];
    __shared__ float Bs[16][128];
    const int t  = threadIdx.x;
    const int tx = t & 15, ty = t >> 4;
    const int m0 = blockIdx.y * 128, n0 = blockIdx.x * 128;

    float acc[8][8];
#pragma unroll
    for (int i = 0; i < 8; ++i)
#pragma unroll
        for (int j = 0; j < 8; ++j) acc[i][j] = 0.f;

    for (int k0 = 0; k0 < K; k0 += 16) {
#pragma unroll
        for (int u = 0; u < 2; ++u) {
            int idx = u * 256 + t;
            int row = idx >> 2;
            int c4  = idx & 3;
            float4 v = *(const float4*)&A[(size_t)(m0 + row) * K + k0 + c4 * 4];
            As[c4 * 4 + 0][row] = v.x;
            As[c4 * 4 + 1][row] = v.y;
            As[c4 * 4 + 2][row] = v.z;
            As[c4 * 4 + 3][row] = v.w;
        }
#pragma unroll
        for (int u = 0; u < 2; ++u) {
            int idx = u * 256 + t;
            int row = idx >> 5;
            int c4  = idx & 31;
            *(float4*)&Bs[row][c4 * 4] =
                *(const float4*)&B[(size_t)(k0 + row) * N + n0 + c4 * 4];
        }
        __syncthreads();
#pragma unroll
        for (int kk = 0; kk < 16; ++kk) {
            float4 a0 = *(float4*)&As[kk][ty * 4];
            float4 a1 = *(float4*)&As[kk][64 + ty * 4];
            float4 b0 = *(float4*)&Bs[kk][tx * 4];
            float4 b1 = *(float4*)&Bs[kk][64 + tx * 4];
            float av[8] = {a0.x, a0.y, a0.z, a0.w, a1.x, a1.y, a1.z, a1.w};
            float bv[8] = {b0.x, b0.y, b0.z, b0.w, b1.x, b1.y, b1.z, b1.w};
#pragma unroll
            for (int i = 0; i < 8; ++i)
#pragma unroll
                for (int j = 0; j < 8; ++j)
                    acc[i][j] = fmaf(av[i], bv[j], acc[i][j]);
        }
        __syncthreads();
    }

    float4 bi0 = *(const float4*)&bias[n0 + tx * 4];
    float4 bi1 = *(const float4*)&bias[n0 + 64 + tx * 4];
    float bb[8] = {bi0.x, bi0.y, bi0.z, bi0.w, bi1.x, bi1.y, bi1.z, bi1.w};
#pragma unroll
    for (int i = 0; i < 8; ++i) {
        int rloc = (i < 4) ? (ty * 4 + i) : (64 + ty * 4 + (i - 4));
        size_t row = (size_t)(m0 + rloc);
        float4 o0 = make_float4(acc[i][0] + bb[0], acc[i][1] + bb[1],
                                acc[i][2] + bb[2], acc[i][3] + bb[3]);
        float4 o1 = make_float4(acc[i][4] + bb[4], acc[i][5] + bb[5],
                                acc[i][6] + bb[6], acc[i][7] + bb[7]);
        *(float4*)&C[row * N + n0 + tx * 4]      = o0;
        *(float4*)&C[row * N + n0 + 64 + tx * 4] = o1;
    }
}

// ---------------------------------------------------------------------------
// Rel-pos precompute (unchanged from R1, fp32).
// rh[h][q][kt], rw[h][q][kw] from UNSCALED q.
// ---------------------------------------------------------------------------
__global__ __launch_bounds__(256)
void relpos_kernel(const float* __restrict__ qkv,
                   const float* __restrict__ rel_pos_h,
                   const float* __restrict__ rel_pos_w,
                   float* __restrict__ rh, float* __restrict__ rw) {
    const int qh = blockIdx.x;
    const int h  = blockIdx.y;
    const int t  = threadIdx.x, tx = t & 15, ty = t >> 4;

    __shared__ float Qt[64][68];
    __shared__ float RH[64][68];
    __shared__ float RW[127][68];

#pragma unroll
    for (int u = 0; u < 4; ++u) {
        int idx = u * 256 + t;
        int row = idx >> 4, c4 = idx & 15;
        *(float4*)&Qt[row][c4 * 4] =
            *(const float4*)&qkv[(size_t)(qh * 64 + row) * (3 * DIM) + h * HD + c4 * 4];
        *(float4*)&RH[row][c4 * 4] =
            *(const float4*)&rel_pos_h[(size_t)(qh - row + 63) * HD + c4 * 4];
    }
#pragma unroll
    for (int u = 0; u < 8; ++u) {
        int idx = u * 256 + t;
        if (idx < 127 * 16) {
            int row = idx >> 4, c4 = idx & 15;
            *(float4*)&RW[row][c4 * 4] =
                *(const float4*)&rel_pos_w[(size_t)row * HD + c4 * 4];
        }
    }
    __syncthreads();

    float acc1[4][4], acc2[4][4];
#pragma unroll
    for (int i = 0; i < 4; ++i)
#pragma unroll
        for (int j = 0; j < 4; ++j) { acc1[i][j] = 0.f; acc2[i][j] = 0.f; }

    for (int c4 = 0; c4 < 16; ++c4) {
        float4 q4[4], r4[4];
#pragma unroll
        for (int i = 0; i < 4; ++i) q4[i] = *(float4*)&Qt[ty * 4 + i][c4 * 4];
#pragma unroll
        for (int j = 0; j < 4; ++j) r4[j] = *(float4*)&RH[tx * 4 + j][c4 * 4];
#pragma unroll
        for (int i = 0; i < 4; ++i)
#pragma unroll
            for (int j = 0; j < 4; ++j) {
                acc1[i][j] = fmaf(q4[i].x, r4[j].x, acc1[i][j]);
                acc1[i][j] = fmaf(q4[i].y, r4[j].y, acc1[i][j]);
                acc1[i][j] = fmaf(q4[i].z, r4[j].z, acc1[i][j]);
                acc1[i][j] = fmaf(q4[i].w, r4[j].w, acc1[i][j]);
            }
#pragma unroll
        for (int i = 0; i < 4; ++i)
#pragma unroll
            for (int j = 0; j < 4; ++j) {
                float4 w4 = *(float4*)&RW[(ty * 4 + i) - (tx * 4 + j) + 63][c4 * 4];
                acc2[i][j] = fmaf(q4[i].x, w4.x, acc2[i][j]);
                acc2[i][j] = fmaf(q4[i].y, w4.y, acc2[i][j]);
                acc2[i][j] = fmaf(q4[i].z, w4.z, acc2[i][j]);
                acc2[i][j] = fmaf(q4[i].w, w4.w, acc2[i][j]);
            }
    }
#pragma unroll
    for (int i = 0; i < 4; ++i) {
        size_t base = ((size_t)h * N_TOK + qh * 64 + ty * 4 + i) * 64 + tx * 4;
        *(float4*)&rh[base] = make_float4(acc1[i][0], acc1[i][1], acc1[i][2], acc1[i][3]);
        *(float4*)&rw[base] = make_float4(acc2[i][0], acc2[i][1], acc2[i][2], acc2[i][3]);
    }
}

// ---------------------------------------------------------------------------
// Flash attention with bf16 MFMA (16x16x32), fp32 accumulate.
// Block = 4 waves = (head h, 64-row q-tile qt). Wave w owns q-rows w*16..+15.
// LDS tiles stride 64 elems (128 B) with XOR swizzle: byte ^= (row&7)<<4.
// Fragment layouts (gfx950, verified in guide):
//   A: row = lane&15, k = (lane>>4)*8 + j   (8 contiguous bf16)
//   B: col = lane&15, k = (lane>>4)*8 + j
//   D: col = lane&15, row = (lane>>4)*4 + reg
// ---------------------------------------------------------------------------
__global__ __launch_bounds__(256, 2)
void attn_mfma(const float* __restrict__ qkv, const float* __restrict__ rh,
               const float* __restrict__ rw, float* __restrict__ out) {
    const int qt = blockIdx.x, h = blockIdx.y;
    const int t = threadIdx.x;
    const int lane = t & 63, w = t >> 6;
    const int c15 = lane & 15, g = lane >> 4;

    __shared__ __align__(16) unsigned short Qs[64 * 64];
    __shared__ __align__(16) unsigned short Ks[64 * 64];
    __shared__ __align__(16) unsigned short Vt[64 * 64];   // [d][key]
    __shared__ __align__(16) unsigned short Ps[4][16 * 64];
    __shared__ __align__(16) float RHs[64 * 68];

    // ---- stage Q (scaled) + RHs
#pragma unroll
    for (int u = 0; u < 4; ++u) {
        int idx = u * 256 + t;
        int row = idx >> 4, c4 = idx & 15;
        float4 qv = *(const float4*)&qkv[(size_t)(qt * 64 + row) * (3 * DIM) + h * HD + c4 * 4];
        us4 p = {f2b(qv.x * 0.125f), f2b(qv.y * 0.125f),
                 f2b(qv.z * 0.125f), f2b(qv.w * 0.125f)};
        int boff = (c4 * 8) ^ ((row & 7) << 4);
        *(us4*)((char*)&Qs[row * 64] + boff) = p;
        *(float4*)&RHs[row * 68 + c4 * 4] =
            *(const float4*)&rh[((size_t)h * N_TOK + qt * 64 + row) * 64 + c4 * 4];
    }
    __syncthreads();

    // Q fragments (held in registers for all 64 k-tiles)
    bf16x8 qf[2];
    {
        int row = w * 16 + c15;
#pragma unroll
        for (int ks = 0; ks < 2; ++ks) {
            int boff = (ks * 64 + g * 16) ^ ((row & 7) << 4);
            qf[ks] = *(bf16x8*)((char*)&Qs[row * 64] + boff);
        }
    }
    // rel_w is kt-invariant: keep in registers, laid out exactly as S-frags
    float rwreg[4][4];
#pragma unroll
    for (int nt = 0; nt < 4; ++nt)
#pragma unroll
        for (int r = 0; r < 4; ++r)
            rwreg[nt][r] = rw[((size_t)h * N_TOK + qt * 64 + w * 16 + g * 4 + r) * 64
                              + nt * 16 + c15];

    float m_r[4], l_r[4];
    f32x4 acc[4];
#pragma unroll
    for (int r = 0; r < 4; ++r) { m_r[r] = -INFINITY; l_r[r] = 0.f; }
#pragma unroll
    for (int nt = 0; nt < 4; ++nt) acc[nt] = f32x4{0.f, 0.f, 0.f, 0.f};

    for (int kt = 0; kt < 64; ++kt) {
        __syncthreads();   // previous iteration's frag reads done
        // ---- stage K (coalesced rows)
#pragma unroll
        for (int u = 0; u < 4; ++u) {
            int idx = u * 256 + t;
            int row = idx >> 4, c4 = idx & 15;
            const float4 kv = *(const float4*)
                &qkv[(size_t)(kt * 64 + row) * (3 * DIM) + DIM + h * HD + c4 * 4];
            us4 p = {f2b(kv.x), f2b(kv.y), f2b(kv.z), f2b(kv.w)};
            int boff = (c4 * 8) ^ ((row & 7) << 4);
            *(us4*)((char*)&Ks[row * 64] + boff) = p;
        }
        // ---- stage V transposed: Vt[d][key]; key = lane -> conflict-free writes
#pragma unroll
        for (int u = 0; u < 4; ++u) {
            int key = lane;
            int c4v = u * 4 + w;
            const float4 vv = *(const float4*)
                &qkv[(size_t)(kt * 64 + key) * (3 * DIM) + 2 * DIM + h * HD + c4v * 4];
            float vals[4] = {vv.x, vv.y, vv.z, vv.w};
#pragma unroll
            for (int j = 0; j < 4; ++j) {
                int d = c4v * 4 + j;
                int boff = (key * 2) ^ ((d & 7) << 4);
                *(unsigned short*)((char*)&Vt[d * 64] + boff) = f2b(vals[j]);
            }
        }
        __syncthreads();

        // ---- S = Q K^T  (wave's 16 rows x 64 keys)
        f32x4 s[4];
#pragma unroll
        for (int nt = 0; nt < 4; ++nt) {
            int krow = nt * 16 + c15;
            int b0 = (g * 16) ^ ((krow & 7) << 4);
            int b1 = (64 + g * 16) ^ ((krow & 7) << 4);
            bf16x8 kf0 = *(bf16x8*)((char*)&Ks[krow * 64] + b0);
            bf16x8 kf1 = *(bf16x8*)((char*)&Ks[krow * 64] + b1);
            f32x4 z = {0.f, 0.f, 0.f, 0.f};
            z = __builtin_amdgcn_mfma_f32_16x16x32_bf16(qf[0], kf0, z, 0, 0, 0);
            z = __builtin_amdgcn_mfma_f32_16x16x32_bf16(qf[1], kf1, z, 0, 0, 0);
            s[nt] = z;
        }
        // ---- rel-pos add (rh broadcast per row, rw from regs)
        float rhv[4];
#pragma unroll
        for (int r = 0; r < 4; ++r)
            rhv[r] = RHs[(w * 16 + g * 4 + r) * 68 + kt];
#pragma unroll
        for (int nt = 0; nt < 4; ++nt)
#pragma unroll
            for (int r = 0; r < 4; ++r)
                s[nt][r] += rhv[r] + rwreg[nt][r];

        // ---- online softmax (rows live in 16-lane column groups)
        float mx[4];
#pragma unroll
        for (int r = 0; r < 4; ++r)
            mx[r] = fmaxf(fmaxf(s[0][r], s[1][r]), fmaxf(s[2][r], s[3][r]));
#pragma unroll
        for (int off = 1; off < 16; off <<= 1)
#pragma unroll
            for (int r = 0; r < 4; ++r)
                mx[r] = fmaxf(mx[r], __shfl_xor(mx[r], off, 64));

        float corr[4], rsum[4];
#pragma unroll
        for (int r = 0; r < 4; ++r) {
            float mnew = fmaxf(m_r[r], mx[r]);
            corr[r] = __expf(m_r[r] - mnew);
            m_r[r] = mnew;
            float su = 0.f;
#pragma unroll
            for (int nt = 0; nt < 4; ++nt) {
                s[nt][r] = __expf(s[nt][r] - mnew);
                su += s[nt][r];
            }
            rsum[r] = su;
        }
#pragma unroll
        for (int off = 1; off < 16; off <<= 1)
#pragma unroll
            for (int r = 0; r < 4; ++r)
                rsum[r] += __shfl_xor(rsum[r], off, 64);
#pragma unroll
        for (int r = 0; r < 4; ++r) {
            l_r[r] = l_r[r] * corr[r] + rsum[r];
#pragma unroll
            for (int nt = 0; nt < 4; ++nt)
                acc[nt][r] *= corr[r];
        }

        // ---- P -> bf16 LDS (per-wave region, no barrier needed)
#pragma unroll
        for (int nt = 0; nt < 4; ++nt)
#pragma unroll
            for (int r = 0; r < 4; ++r) {
                int row = g * 4 + r;
                int boff = ((nt * 16 + c15) * 2) ^ ((row & 7) << 4);
                *(unsigned short*)((char*)&Ps[w][row * 64] + boff) = f2b(s[nt][r]);
            }

        // ---- O += P V
#pragma unroll
        for (int ks = 0; ks < 2; ++ks) {
            int pb = (ks * 64 + g * 16) ^ ((c15 & 7) << 4);
            bf16x8 pf = *(bf16x8*)((char*)&Ps[w][c15 * 64] + pb);
#pragma unroll
            for (int nt = 0; nt < 4; ++nt) {
                int drow = nt * 16 + c15;
                int vb = (ks * 64 + g * 16) ^ ((drow & 7) << 4);
                bf16x8 vf = *(bf16x8*)((char*)&Vt[drow * 64] + vb);
                acc[nt] = __builtin_amdgcn_mfma_f32_16x16x32_bf16(pf, vf, acc[nt], 0, 0, 0);
            }
        }
    }

    // ---- epilogue
#pragma unroll
    for (int r = 0; r < 4; ++r) {
        float inv = 1.0f / l_r[r];
        size_t orow = (size_t)(qt * 64 + w * 16 + g * 4 + r) * DIM + h * HD;
#pragma unroll
        for (int nt = 0; nt < 4; ++nt)
            out[orow + nt * 16 + c15] = acc[nt][r] * inv;
    }
}

// ---------------------------------------------------------------------------
extern "C" void kernel_launch(void* const* d_in, const int* in_sizes, int n_in,
                              void* d_out, int out_size, void* d_ws, size_t ws_size,
                              hipStream_t stream) {
    const float* x      = (const float*)d_in[0];
    const float* w_qkv  = (const float*)d_in[1];
    const float* b_qkv  = (const float*)d_in[2];
    const float* w_proj = (const float*)d_in[3];
    const float* b_proj = (const float*)d_in[4];
    const float* rph    = (const float*)d_in[5];
    const float* rpw    = (const float*)d_in[6];
    float* out = (float*)d_out;

    float* ws  = (float*)d_ws;
    float* qkv = ws;
    float* rh  = qkv + (size_t)N_TOK * 3 * DIM;
    float* rw  = rh + (size_t)NH * N_TOK * 64;
    float* ao  = rw + (size_t)NH * N_TOK * 64;

    gemm_bias<N_TOK, 3 * DIM, DIM><<<dim3(18, 32), 256, 0, stream>>>(x, w_qkv, b_qkv, qkv);
    relpos_kernel<<<dim3(64, NH), 256, 0, stream>>>(qkv, rph, rpw, rh, rw);
    attn_mfma<<<dim3(64, NH), 256, 0, stream>>>(qkv, rh, rw, ao);
    gemm_bias<N_TOK, DIM, DIM><<<dim3(6, 32), 256, 0, stream>>>(ao, w_proj, b_proj, out);
}

// Round 4
// 405.740 us; speedup vs baseline: 4.9448x; 1.6440x over previous
//
#include <hip/hip_runtime.h>
#include <math.h>

#define N_TOK 4096
#define DIM   768
#define NH    12
#define HD    64

typedef __attribute__((ext_vector_type(8))) short bf16x8;
typedef __attribute__((ext_vector_type(4))) float f32x4;
typedef __attribute__((ext_vector_type(4))) unsigned short us4;

__device__ inline unsigned short f2b(float f) {   // fp32 -> bf16 RNE
    union { float f; unsigned int u; } v; v.f = f;
    unsigned int r = v.u + 0x7FFFu + ((v.u >> 16) & 1u);
    return (unsigned short)(r >> 16);
}
__device__ inline float b2f(unsigned short u) {
    union { unsigned int u; float f; } v; v.u = ((unsigned int)u) << 16;
    return v.f;
}
__device__ inline void gload16(const void* g, void* l) {
    __builtin_amdgcn_global_load_lds(
        (const __attribute__((address_space(1))) unsigned int*)g,
        (__attribute__((address_space(3))) unsigned int*)l, 16, 0, 0);
}

// ---------------------------------------------------------------------------
// fp32 -> (hi, lo) bf16 split, elementwise.  n4 = elems/4.
// ---------------------------------------------------------------------------
__global__ __launch_bounds__(256)
void conv_split(const float* __restrict__ X, unsigned short* __restrict__ hi,
                unsigned short* __restrict__ lo, int n4) {
    int i = blockIdx.x * 256 + threadIdx.x;
    int stride = gridDim.x * 256;
    for (; i < n4; i += stride) {
        float4 v = ((const float4*)X)[i];
        us4 h, l;
        h.x = f2b(v.x); l.x = f2b(v.x - b2f(h.x));
        h.y = f2b(v.y); l.y = f2b(v.y - b2f(h.y));
        h.z = f2b(v.z); l.z = f2b(v.z - b2f(h.z));
        h.w = f2b(v.w); l.w = f2b(v.w - b2f(h.w));
        ((us4*)hi)[i] = h;
        ((us4*)lo)[i] = l;
    }
}

// ---------------------------------------------------------------------------
// W[K][N] fp32 -> T[N][K] split bf16 (hi, lo). 64x64 tiles.
// ---------------------------------------------------------------------------
__global__ __launch_bounds__(256)
void transpose_split(const float* __restrict__ W, unsigned short* __restrict__ Thi,
                     unsigned short* __restrict__ Tlo, int K, int N) {
    __shared__ float tile[64][65];
    const int t = threadIdx.x;
    const int k0 = blockIdx.y * 64, n0 = blockIdx.x * 64;
#pragma unroll
    for (int u = 0; u < 4; ++u) {
        int idx = u * 256 + t;
        int r = idx >> 4, c4 = idx & 15;
        float4 v = *(const float4*)&W[(size_t)(k0 + r) * N + n0 + c4 * 4];
        tile[r][c4 * 4 + 0] = v.x; tile[r][c4 * 4 + 1] = v.y;
        tile[r][c4 * 4 + 2] = v.z; tile[r][c4 * 4 + 3] = v.w;
    }
    __syncthreads();
#pragma unroll
    for (int u = 0; u < 4; ++u) {
        int idx = u * 256 + t;
        int col = idx >> 4, c4 = idx & 15;
        float a0 = tile[c4 * 4 + 0][col], a1 = tile[c4 * 4 + 1][col];
        float a2 = tile[c4 * 4 + 2][col], a3 = tile[c4 * 4 + 3][col];
        us4 h, l;
        h.x = f2b(a0); l.x = f2b(a0 - b2f(h.x));
        h.y = f2b(a1); l.y = f2b(a1 - b2f(h.y));
        h.z = f2b(a2); l.z = f2b(a2 - b2f(h.z));
        h.w = f2b(a3); l.w = f2b(a3 - b2f(h.w));
        size_t o = (size_t)(n0 + col) * K + k0 + c4 * 4;
        *(us4*)&Thi[o] = h;
        *(us4*)&Tlo[o] = l;
    }
}

// ---------------------------------------------------------------------------
// Split-bf16 MFMA GEMM: C = A * B + bias, A[M][K] as (Ahi+Alo), B as BT[N][K]
// split. acc += ah*bh + ah*bl + al*bh  (~fp32 accuracy; lo*lo dropped).
// 128x128 tile, 4 waves (wave = 64x64 quadrant), BK=32.
// LDS: 4 arrays of 128 rows x 32 bf16 (64B rows), chunk swizzle g ^= (row&3).
// Staged via global_load_lds: linear dest, inverse-swizzled source.
// MODE 0: Cout[M][N] fp32.  MODE 1 (qkv): qf32[M][768] (q cols only) +
//         qkvbf[(which*NH+h)][tok][64] bf16, q pre-scaled by 0.125.
// ---------------------------------------------------------------------------
template<int M, int N, int K, int MODE>
__global__ __launch_bounds__(256)
void gemm_split(const unsigned short* __restrict__ Ahi, const unsigned short* __restrict__ Alo,
                const unsigned short* __restrict__ BThi, const unsigned short* __restrict__ BTlo,
                const float* __restrict__ bias, float* __restrict__ Cout,
                float* __restrict__ qf32, unsigned short* __restrict__ qkvbf) {
    __shared__ __align__(16) char smem[32768];
    const int t = threadIdx.x, lane = t & 63, w = t >> 6;
    const int c15 = lane & 15, g = lane >> 4;
    const int m0 = blockIdx.y * 128, n0 = blockIdx.x * 128;
    const int wm = (w >> 1) * 64, wn = (w & 1) * 64;

    f32x4 acc[4][4];
#pragma unroll
    for (int i = 0; i < 4; ++i)
#pragma unroll
        for (int j = 0; j < 4; ++j) acc[i][j] = f32x4{0.f, 0.f, 0.f, 0.f};

    for (int k0 = 0; k0 < K; k0 += 32) {
        __syncthreads();
#pragma unroll
        for (int p = 0; p < 2; ++p) {
            int off = p * 4096 + w * 1024 + lane * 16;  // byte off in one array
            int row = off >> 6;
            int gs  = ((off >> 4) & 3) ^ (row & 3);     // inverse-swizzled src chunk
            size_t ae = (size_t)(m0 + row) * K + k0 + gs * 8;
            size_t be = (size_t)(n0 + row) * K + k0 + gs * 8;
            char* dst = smem + p * 4096 + w * 1024;     // wave-uniform base
            gload16(Ahi  + ae, dst);
            gload16(Alo  + ae, dst + 8192);
            gload16(BThi + be, dst + 16384);
            gload16(BTlo + be, dst + 24576);
        }
        __syncthreads();

        bf16x8 ah[4], al[4], bh[4], bl[4];
#pragma unroll
        for (int i = 0; i < 4; ++i) {
            int ra = wm + i * 16 + c15;
            int boa = ra * 64 + ((g ^ (ra & 3)) << 4);
            ah[i] = *(const bf16x8*)(smem + boa);
            al[i] = *(const bf16x8*)(smem + 8192 + boa);
            int rb = wn + i * 16 + c15;
            int bob = rb * 64 + ((g ^ (rb & 3)) << 4);
            bh[i] = *(const bf16x8*)(smem + 16384 + bob);
            bl[i] = *(const bf16x8*)(smem + 24576 + bob);
        }
#pragma unroll
        for (int i = 0; i < 4; ++i)
#pragma unroll
            for (int j = 0; j < 4; ++j) {
                acc[i][j] = __builtin_amdgcn_mfma_f32_16x16x32_bf16(ah[i], bh[j], acc[i][j], 0, 0, 0);
                acc[i][j] = __builtin_amdgcn_mfma_f32_16x16x32_bf16(ah[i], bl[j], acc[i][j], 0, 0, 0);
                acc[i][j] = __builtin_amdgcn_mfma_f32_16x16x32_bf16(al[i], bh[j], acc[i][j], 0, 0, 0);
            }
    }

    if (MODE == 0) {
#pragma unroll
        for (int j = 0; j < 4; ++j) {
            float bb = bias[n0 + wn + j * 16 + c15];
#pragma unroll
            for (int i = 0; i < 4; ++i)
#pragma unroll
                for (int r = 0; r < 4; ++r) {
                    int mm = m0 + wm + i * 16 + g * 4 + r;
                    Cout[(size_t)mm * N + n0 + wn + j * 16 + c15] = acc[i][j][r] + bb;
                }
        }
    } else {
        const int nq = n0 + wn;              // wave col base: single head
        const int which = nq / 768;
        const int hcol = (nq % 768) >> 6;
        const float scale = (which == 0) ? 0.125f : 1.0f;
#pragma unroll
        for (int j = 0; j < 4; ++j) {
            int d = j * 16 + c15;
            float bb = bias[nq + d];
#pragma unroll
            for (int i = 0; i < 4; ++i)
#pragma unroll
                for (int r = 0; r < 4; ++r) {
                    int mm = m0 + wm + i * 16 + g * 4 + r;
                    float val = acc[i][j][r] + bb;
                    if (which == 0) qf32[(size_t)mm * 768 + nq + d] = val;
                    qkvbf[((size_t)(which * NH + hcol) * N_TOK + mm) * 64 + d] =
                        f2b(val * scale);
                }
        }
    }
}

// ---------------------------------------------------------------------------
// Rel-pos precompute from UNSCALED fp32 q (qf32[tok][768]).
// Outputs bf16 tables rh/rw [h][tok][64].
// ---------------------------------------------------------------------------
__global__ __launch_bounds__(256)
void relpos_kernel(const float* __restrict__ qf32,
                   const float* __restrict__ rel_pos_h,
                   const float* __restrict__ rel_pos_w,
                   unsigned short* __restrict__ rh, unsigned short* __restrict__ rw) {
    const int qh = blockIdx.x;
    const int h  = blockIdx.y;
    const int t  = threadIdx.x, tx = t & 15, ty = t >> 4;

    __shared__ float Qt[64][68];
    __shared__ float RH[64][68];
    __shared__ float RW[127][68];

#pragma unroll
    for (int u = 0; u < 4; ++u) {
        int idx = u * 256 + t;
        int row = idx >> 4, c4 = idx & 15;
        *(float4*)&Qt[row][c4 * 4] =
            *(const float4*)&qf32[(size_t)(qh * 64 + row) * 768 + h * HD + c4 * 4];
        *(float4*)&RH[row][c4 * 4] =
            *(const float4*)&rel_pos_h[(size_t)(qh - row + 63) * HD + c4 * 4];
    }
#pragma unroll
    for (int u = 0; u < 8; ++u) {
        int idx = u * 256 + t;
        if (idx < 127 * 16) {
            int row = idx >> 4, c4 = idx & 15;
            *(float4*)&RW[row][c4 * 4] =
                *(const float4*)&rel_pos_w[(size_t)row * HD + c4 * 4];
        }
    }
    __syncthreads();

    float acc1[4][4], acc2[4][4];
#pragma unroll
    for (int i = 0; i < 4; ++i)
#pragma unroll
        for (int j = 0; j < 4; ++j) { acc1[i][j] = 0.f; acc2[i][j] = 0.f; }

    for (int c4 = 0; c4 < 16; ++c4) {
        float4 q4[4], r4[4];
#pragma unroll
        for (int i = 0; i < 4; ++i) q4[i] = *(float4*)&Qt[ty * 4 + i][c4 * 4];
#pragma unroll
        for (int j = 0; j < 4; ++j) r4[j] = *(float4*)&RH[tx * 4 + j][c4 * 4];
#pragma unroll
        for (int i = 0; i < 4; ++i)
#pragma unroll
            for (int j = 0; j < 4; ++j) {
                acc1[i][j] = fmaf(q4[i].x, r4[j].x, acc1[i][j]);
                acc1[i][j] = fmaf(q4[i].y, r4[j].y, acc1[i][j]);
                acc1[i][j] = fmaf(q4[i].z, r4[j].z, acc1[i][j]);
                acc1[i][j] = fmaf(q4[i].w, r4[j].w, acc1[i][j]);
            }
#pragma unroll
        for (int i = 0; i < 4; ++i)
#pragma unroll
            for (int j = 0; j < 4; ++j) {
                float4 w4 = *(float4*)&RW[(ty * 4 + i) - (tx * 4 + j) + 63][c4 * 4];
                acc2[i][j] = fmaf(q4[i].x, w4.x, acc2[i][j]);
                acc2[i][j] = fmaf(q4[i].y, w4.y, acc2[i][j]);
                acc2[i][j] = fmaf(q4[i].z, w4.z, acc2[i][j]);
                acc2[i][j] = fmaf(q4[i].w, w4.w, acc2[i][j]);
            }
    }
#pragma unroll
    for (int i = 0; i < 4; ++i) {
        size_t base = ((size_t)h * N_TOK + qh * 64 + ty * 4 + i) * 64 + tx * 4;
        us4 h4, w4;
        h4.x = f2b(acc1[i][0]); h4.y = f2b(acc1[i][1]);
        h4.z = f2b(acc1[i][2]); h4.w = f2b(acc1[i][3]);
        w4.x = f2b(acc2[i][0]); w4.y = f2b(acc2[i][1]);
        w4.z = f2b(acc2[i][2]); w4.w = f2b(acc2[i][3]);
        *(us4*)&rh[base] = h4;
        *(us4*)&rw[base] = w4;
    }
}

// ---------------------------------------------------------------------------
// Flash attention, bf16 MFMA. Sources are pre-converted bf16 head-major
// qkvbf[(which*NH+h)][tok][64] (q pre-scaled). Writes ao as split bf16.
// ---------------------------------------------------------------------------
__global__ __launch_bounds__(256, 2)
void attn_mfma(const unsigned short* __restrict__ qkvbf,
               const unsigned short* __restrict__ rh,
               const unsigned short* __restrict__ rw,
               unsigned short* __restrict__ aohi, unsigned short* __restrict__ aolo) {
    const int qt = blockIdx.x, h = blockIdx.y;
    const int t = threadIdx.x;
    const int lane = t & 63, w = t >> 6;
    const int c15 = lane & 15, g = lane >> 4;

    const unsigned short* qbf = qkvbf + ((size_t)(0 * NH + h)) * N_TOK * 64;
    const unsigned short* kbf = qkvbf + ((size_t)(1 * NH + h)) * N_TOK * 64;
    const unsigned short* vbf = qkvbf + ((size_t)(2 * NH + h)) * N_TOK * 64;

    __shared__ __align__(16) unsigned short Qs[64 * 64];
    __shared__ __align__(16) unsigned short Ks[64 * 64];
    __shared__ __align__(16) unsigned short Vt[64 * 64];   // [d][key]
    __shared__ __align__(16) unsigned short Ps[4][16 * 64];
    __shared__ __align__(16) float RHs[64 * 68];

    // ---- stage Q (pre-scaled bf16) + RHs (bf16 -> f32)
#pragma unroll
    for (int u = 0; u < 2; ++u) {
        int idx = u * 256 + t;              // 0..511
        int row = idx >> 3, ch = idx & 7;
        bf16x8 v = *(const bf16x8*)&qbf[(size_t)(qt * 64 + row) * 64 + ch * 8];
        int boff = (ch * 16) ^ ((row & 7) << 4);
        *(bf16x8*)((char*)&Qs[row * 64] + boff) = v;
    }
#pragma unroll
    for (int u = 0; u < 4; ++u) {
        int idx = u * 256 + t;
        int row = idx >> 4, c4 = idx & 15;
        us4 v = *(const us4*)&rh[((size_t)h * N_TOK + qt * 64 + row) * 64 + c4 * 4];
        float4 f = make_float4(b2f(v.x), b2f(v.y), b2f(v.z), b2f(v.w));
        *(float4*)&RHs[row * 68 + c4 * 4] = f;
    }
    __syncthreads();

    bf16x8 qf[2];
    {
        int row = w * 16 + c15;
#pragma unroll
        for (int ks = 0; ks < 2; ++ks) {
            int boff = (ks * 64 + g * 16) ^ ((row & 7) << 4);
            qf[ks] = *(bf16x8*)((char*)&Qs[row * 64] + boff);
        }
    }
    float rwreg[4][4];
#pragma unroll
    for (int nt = 0; nt < 4; ++nt)
#pragma unroll
        for (int r = 0; r < 4; ++r)
            rwreg[nt][r] = b2f(rw[((size_t)h * N_TOK + qt * 64 + w * 16 + g * 4 + r) * 64
                                  + nt * 16 + c15]);

    float m_r[4], l_r[4];
    f32x4 acc[4];
#pragma unroll
    for (int r = 0; r < 4; ++r) { m_r[r] = -INFINITY; l_r[r] = 0.f; }
#pragma unroll
    for (int nt = 0; nt < 4; ++nt) acc[nt] = f32x4{0.f, 0.f, 0.f, 0.f};

    for (int kt = 0; kt < 64; ++kt) {
        __syncthreads();
        // ---- stage K: 1x b128 load + 1x ds_write_b128 per thread
#pragma unroll
        for (int u = 0; u < 2; ++u) {
            int idx = u * 256 + t;
            int row = idx >> 3, ch = idx & 7;
            bf16x8 v = *(const bf16x8*)&kbf[(size_t)(kt * 64 + row) * 64 + ch * 8];
            int boff = (ch * 16) ^ ((row & 7) << 4);
            *(bf16x8*)((char*)&Ks[row * 64] + boff) = v;
        }
        // ---- stage V transposed, b32-paired writes (keys kp, kp+1)
        {
            int kp = (t & 31) * 2;
            int d0 = (t >> 5) * 8;
            bf16x8 r0 = *(const bf16x8*)&vbf[(size_t)(kt * 64 + kp) * 64 + d0];
            bf16x8 r1 = *(const bf16x8*)&vbf[(size_t)(kt * 64 + kp + 1) * 64 + d0];
#pragma unroll
            for (int j = 0; j < 8; ++j) {
                int d = d0 + j;
                unsigned int pk = (unsigned int)(unsigned short)r0[j]
                                | ((unsigned int)(unsigned short)r1[j] << 16);
                int boff = (kp * 2) ^ ((d & 7) << 4);
                *(unsigned int*)((char*)&Vt[d * 64] + boff) = pk;
            }
        }
        __syncthreads();

        // ---- S = Q K^T
        f32x4 s[4];
#pragma unroll
        for (int nt = 0; nt < 4; ++nt) {
            int krow = nt * 16 + c15;
            int b0 = (g * 16) ^ ((krow & 7) << 4);
            int b1 = (64 + g * 16) ^ ((krow & 7) << 4);
            bf16x8 kf0 = *(bf16x8*)((char*)&Ks[krow * 64] + b0);
            bf16x8 kf1 = *(bf16x8*)((char*)&Ks[krow * 64] + b1);
            f32x4 z = {0.f, 0.f, 0.f, 0.f};
            z = __builtin_amdgcn_mfma_f32_16x16x32_bf16(qf[0], kf0, z, 0, 0, 0);
            z = __builtin_amdgcn_mfma_f32_16x16x32_bf16(qf[1], kf1, z, 0, 0, 0);
            s[nt] = z;
        }
        float rhv[4];
#pragma unroll
        for (int r = 0; r < 4; ++r)
            rhv[r] = RHs[(w * 16 + g * 4 + r) * 68 + kt];
#pragma unroll
        for (int nt = 0; nt < 4; ++nt)
#pragma unroll
            for (int r = 0; r < 4; ++r)
                s[nt][r] += rhv[r] + rwreg[nt][r];

        // ---- online softmax
        float mx[4];
#pragma unroll
        for (int r = 0; r < 4; ++r)
            mx[r] = fmaxf(fmaxf(s[0][r], s[1][r]), fmaxf(s[2][r], s[3][r]));
#pragma unroll
        for (int off = 1; off < 16; off <<= 1)
#pragma unroll
            for (int r = 0; r < 4; ++r)
                mx[r] = fmaxf(mx[r], __shfl_xor(mx[r], off, 64));

        float corr[4], rsum[4];
#pragma unroll
        for (int r = 0; r < 4; ++r) {
            float mnew = fmaxf(m_r[r], mx[r]);
            corr[r] = __expf(m_r[r] - mnew);
            m_r[r] = mnew;
            float su = 0.f;
#pragma unroll
            for (int nt = 0; nt < 4; ++nt) {
                s[nt][r] = __expf(s[nt][r] - mnew);
                su += s[nt][r];
            }
            rsum[r] = su;
        }
#pragma unroll
        for (int off = 1; off < 16; off <<= 1)
#pragma unroll
            for (int r = 0; r < 4; ++r)
                rsum[r] += __shfl_xor(rsum[r], off, 64);
#pragma unroll
        for (int r = 0; r < 4; ++r) {
            l_r[r] = l_r[r] * corr[r] + rsum[r];
#pragma unroll
            for (int nt = 0; nt < 4; ++nt)
                acc[nt][r] *= corr[r];
        }

        // ---- P -> bf16 LDS (per-wave region)
#pragma unroll
        for (int nt = 0; nt < 4; ++nt)
#pragma unroll
            for (int r = 0; r < 4; ++r) {
                int row = g * 4 + r;
                int boff = ((nt * 16 + c15) * 2) ^ ((row & 7) << 4);
                *(unsigned short*)((char*)&Ps[w][row * 64] + boff) = f2b(s[nt][r]);
            }

        // ---- O += P V
#pragma unroll
        for (int ks = 0; ks < 2; ++ks) {
            int pb = (ks * 64 + g * 16) ^ ((c15 & 7) << 4);
            bf16x8 pf = *(bf16x8*)((char*)&Ps[w][c15 * 64] + pb);
#pragma unroll
            for (int nt = 0; nt < 4; ++nt) {
                int drow = nt * 16 + c15;
                int vb = (ks * 64 + g * 16) ^ ((drow & 7) << 4);
                bf16x8 vf = *(bf16x8*)((char*)&Vt[drow * 64] + vb);
                acc[nt] = __builtin_amdgcn_mfma_f32_16x16x32_bf16(pf, vf, acc[nt], 0, 0, 0);
            }
        }
    }

    // ---- epilogue: ao as split bf16 (A-operand for proj GEMM)
#pragma unroll
    for (int r = 0; r < 4; ++r) {
        float inv = 1.0f / l_r[r];
        size_t orow = (size_t)(qt * 64 + w * 16 + g * 4 + r) * 768 + h * HD;
#pragma unroll
        for (int nt = 0; nt < 4; ++nt) {
            float o = acc[nt][r] * inv;
            unsigned short hi = f2b(o);
            unsigned short lo = f2b(o - b2f(hi));
            aohi[orow + nt * 16 + c15] = hi;
            aolo[orow + nt * 16 + c15] = lo;
        }
    }
}

// ---------------------------------------------------------------------------
extern "C" void kernel_launch(void* const* d_in, const int* in_sizes, int n_in,
                              void* d_out, int out_size, void* d_ws, size_t ws_size,
                              hipStream_t stream) {
    const float* x      = (const float*)d_in[0];
    const float* w_qkv  = (const float*)d_in[1];
    const float* b_qkv  = (const float*)d_in[2];
    const float* w_proj = (const float*)d_in[3];
    const float* b_proj = (const float*)d_in[4];
    const float* rph    = (const float*)d_in[5];
    const float* rpw    = (const float*)d_in[6];
    float* out = (float*)d_out;

    char* p = (char*)d_ws;
    float* qf32           = (float*)p;          p += (size_t)N_TOK * 768 * 4;       // 12.6 MB
    unsigned short* qkvbf = (unsigned short*)p; p += (size_t)3 * NH * N_TOK * 64 * 2; // 18.9 MB
    unsigned short* rhbf  = (unsigned short*)p; p += (size_t)NH * N_TOK * 64 * 2;   // 6.3 MB
    unsigned short* rwbf  = (unsigned short*)p; p += (size_t)NH * N_TOK * 64 * 2;   // 6.3 MB
    unsigned short* xhi   = (unsigned short*)p; p += (size_t)N_TOK * 768 * 2;       // 6.3 MB
    unsigned short* xlo   = (unsigned short*)p; p += (size_t)N_TOK * 768 * 2;       // 6.3 MB
    unsigned short* wqThi = (unsigned short*)p; p += (size_t)2304 * 768 * 2;        // 3.5 MB
    unsigned short* wqTlo = (unsigned short*)p; p += (size_t)2304 * 768 * 2;
    unsigned short* wpThi = (unsigned short*)p; p += (size_t)768 * 768 * 2;         // 1.2 MB
    unsigned short* wpTlo = (unsigned short*)p; p += (size_t)768 * 768 * 2;
    // ao aliases x-split space (x consumed by qkv GEMM before attn writes ao)
    unsigned short* aohi = xhi;
    unsigned short* aolo = xlo;

    conv_split<<<1024, 256, 0, stream>>>(x, xhi, xlo, N_TOK * 768 / 4);
    transpose_split<<<dim3(36, 12), 256, 0, stream>>>(w_qkv, wqThi, wqTlo, 768, 2304);
    transpose_split<<<dim3(12, 12), 256, 0, stream>>>(w_proj, wpThi, wpTlo, 768, 768);

    gemm_split<N_TOK, 2304, 768, 1><<<dim3(18, 32), 256, 0, stream>>>(
        xhi, xlo, wqThi, wqTlo, b_qkv, nullptr, qf32, qkvbf);

    relpos_kernel<<<dim3(64, NH), 256, 0, stream>>>(qf32, rph, rpw, rhbf, rwbf);

    attn_mfma<<<dim3(64, NH), 256, 0, stream>>>(qkvbf, rhbf, rwbf, aohi, aolo);

    gemm_split<N_TOK, 768, 768, 0><<<dim3(6, 32), 256, 0, stream>>>(
        aohi, aolo, wpThi, wpTlo, b_proj, out, nullptr, nullptr);
}

// Round 5
// 367.623 us; speedup vs baseline: 5.4575x; 1.1037x over previous
//
#include <hip/hip_runtime.h>
#include <math.h>

#define N_TOK 4096
#define DIM   768
#define NH    12
#define HD    64

typedef __attribute__((ext_vector_type(8))) short bf16x8;
typedef __attribute__((ext_vector_type(4))) float f32x4;
typedef __attribute__((ext_vector_type(4))) unsigned short us4;

__device__ inline unsigned short f2b(float f) {   // fp32 -> bf16 RNE
    union { float f; unsigned int u; } v; v.f = f;
    unsigned int r = v.u + 0x7FFFu + ((v.u >> 16) & 1u);
    return (unsigned short)(r >> 16);
}
__device__ inline float b2f(unsigned short u) {
    union { unsigned int u; float f; } v; v.u = ((unsigned int)u) << 16;
    return v.f;
}
__device__ inline unsigned int pk2(float lo, float hi) {   // 2x f32 -> packed bf16 RNE
    unsigned int u;
    asm("v_cvt_pk_bf16_f32 %0, %1, %2" : "=v"(u) : "v"(lo), "v"(hi));
    return u;
}
__device__ inline void gload16(const void* g, void* l) {
    __builtin_amdgcn_global_load_lds(
        (const __attribute__((address_space(1))) unsigned int*)g,
        (__attribute__((address_space(3))) unsigned int*)l, 16, 0, 0);
}

// ---------------------------------------------------------------------------
// fp32 -> (hi, lo) bf16 split, elementwise.  n4 = elems/4.
// ---------------------------------------------------------------------------
__global__ __launch_bounds__(256)
void conv_split(const float* __restrict__ X, unsigned short* __restrict__ hi,
                unsigned short* __restrict__ lo, int n4) {
    int i = blockIdx.x * 256 + threadIdx.x;
    int stride = gridDim.x * 256;
    for (; i < n4; i += stride) {
        float4 v = ((const float4*)X)[i];
        us4 h, l;
        h.x = f2b(v.x); l.x = f2b(v.x - b2f(h.x));
        h.y = f2b(v.y); l.y = f2b(v.y - b2f(h.y));
        h.z = f2b(v.z); l.z = f2b(v.z - b2f(h.z));
        h.w = f2b(v.w); l.w = f2b(v.w - b2f(h.w));
        ((us4*)hi)[i] = h;
        ((us4*)lo)[i] = l;
    }
}

// ---------------------------------------------------------------------------
// W[K][N] fp32 -> T[N][K] split bf16 (hi, lo). 64x64 tiles.
// ---------------------------------------------------------------------------
__global__ __launch_bounds__(256)
void transpose_split(const float* __restrict__ W, unsigned short* __restrict__ Thi,
                     unsigned short* __restrict__ Tlo, int K, int N) {
    __shared__ float tile[64][65];
    const int t = threadIdx.x;
    const int k0 = blockIdx.y * 64, n0 = blockIdx.x * 64;
#pragma unroll
    for (int u = 0; u < 4; ++u) {
        int idx = u * 256 + t;
        int r = idx >> 4, c4 = idx & 15;
        float4 v = *(const float4*)&W[(size_t)(k0 + r) * N + n0 + c4 * 4];
        tile[r][c4 * 4 + 0] = v.x; tile[r][c4 * 4 + 1] = v.y;
        tile[r][c4 * 4 + 2] = v.z; tile[r][c4 * 4 + 3] = v.w;
    }
    __syncthreads();
#pragma unroll
    for (int u = 0; u < 4; ++u) {
        int idx = u * 256 + t;
        int col = idx >> 4, c4 = idx & 15;
        float a0 = tile[c4 * 4 + 0][col], a1 = tile[c4 * 4 + 1][col];
        float a2 = tile[c4 * 4 + 2][col], a3 = tile[c4 * 4 + 3][col];
        us4 h, l;
        h.x = f2b(a0); l.x = f2b(a0 - b2f(h.x));
        h.y = f2b(a1); l.y = f2b(a1 - b2f(h.y));
        h.z = f2b(a2); l.z = f2b(a2 - b2f(h.z));
        h.w = f2b(a3); l.w = f2b(a3 - b2f(h.w));
        size_t o = (size_t)(n0 + col) * K + k0 + c4 * 4;
        *(us4*)&Thi[o] = h;
        *(us4*)&Tlo[o] = l;
    }
}

// ---------------------------------------------------------------------------
// Split-bf16 MFMA GEMM: C = A * B + bias (see R4 comments). XCD-swizzled.
// ---------------------------------------------------------------------------
template<int M, int N, int K, int MODE>
__global__ __launch_bounds__(256)
void gemm_split(const unsigned short* __restrict__ Ahi, const unsigned short* __restrict__ Alo,
                const unsigned short* __restrict__ BThi, const unsigned short* __restrict__ BTlo,
                const float* __restrict__ bias, float* __restrict__ Cout,
                float* __restrict__ qf32, unsigned short* __restrict__ qkvbf) {
    __shared__ __align__(16) char smem[32768];
    const int t = threadIdx.x, lane = t & 63, w = t >> 6;
    const int c15 = lane & 15, g = lane >> 4;
    // XCD-aware swizzle (nwg % 8 == 0 for both instantiations)
    const int nwg = gridDim.x * gridDim.y;
    int lin = blockIdx.y * gridDim.x + blockIdx.x;
    lin = (lin & 7) * (nwg >> 3) + (lin >> 3);
    const int m0 = (lin / gridDim.x) * 128, n0 = (lin % gridDim.x) * 128;
    const int wm = (w >> 1) * 64, wn = (w & 1) * 64;

    f32x4 acc[4][4];
#pragma unroll
    for (int i = 0; i < 4; ++i)
#pragma unroll
        for (int j = 0; j < 4; ++j) acc[i][j] = f32x4{0.f, 0.f, 0.f, 0.f};

    for (int k0 = 0; k0 < K; k0 += 32) {
        __syncthreads();
#pragma unroll
        for (int p = 0; p < 2; ++p) {
            int off = p * 4096 + w * 1024 + lane * 16;  // byte off in one array
            int row = off >> 6;
            int gs  = ((off >> 4) & 3) ^ (row & 3);     // inverse-swizzled src chunk
            size_t ae = (size_t)(m0 + row) * K + k0 + gs * 8;
            size_t be = (size_t)(n0 + row) * K + k0 + gs * 8;
            char* dst = smem + p * 4096 + w * 1024;     // wave-uniform base
            gload16(Ahi  + ae, dst);
            gload16(Alo  + ae, dst + 8192);
            gload16(BThi + be, dst + 16384);
            gload16(BTlo + be, dst + 24576);
        }
        __syncthreads();

        bf16x8 ah[4], al[4], bh[4], bl[4];
#pragma unroll
        for (int i = 0; i < 4; ++i) {
            int ra = wm + i * 16 + c15;
            int boa = ra * 64 + ((g ^ (ra & 3)) << 4);
            ah[i] = *(const bf16x8*)(smem + boa);
            al[i] = *(const bf16x8*)(smem + 8192 + boa);
            int rb = wn + i * 16 + c15;
            int bob = rb * 64 + ((g ^ (rb & 3)) << 4);
            bh[i] = *(const bf16x8*)(smem + 16384 + bob);
            bl[i] = *(const bf16x8*)(smem + 24576 + bob);
        }
#pragma unroll
        for (int i = 0; i < 4; ++i)
#pragma unroll
            for (int j = 0; j < 4; ++j) {
                acc[i][j] = __builtin_amdgcn_mfma_f32_16x16x32_bf16(ah[i], bh[j], acc[i][j], 0, 0, 0);
                acc[i][j] = __builtin_amdgcn_mfma_f32_16x16x32_bf16(ah[i], bl[j], acc[i][j], 0, 0, 0);
                acc[i][j] = __builtin_amdgcn_mfma_f32_16x16x32_bf16(al[i], bh[j], acc[i][j], 0, 0, 0);
            }
    }

    if (MODE == 0) {
#pragma unroll
        for (int j = 0; j < 4; ++j) {
            float bb = bias[n0 + wn + j * 16 + c15];
#pragma unroll
            for (int i = 0; i < 4; ++i)
#pragma unroll
                for (int r = 0; r < 4; ++r) {
                    int mm = m0 + wm + i * 16 + g * 4 + r;
                    Cout[(size_t)mm * N + n0 + wn + j * 16 + c15] = acc[i][j][r] + bb;
                }
        }
    } else {
        const int nq = n0 + wn;              // wave col base: single head
        const int which = nq / 768;
        const int hcol = (nq % 768) >> 6;
        const float scale = (which == 0) ? 0.125f : 1.0f;
#pragma unroll
        for (int j = 0; j < 4; ++j) {
            int d = j * 16 + c15;
            float bb = bias[nq + d];
#pragma unroll
            for (int i = 0; i < 4; ++i)
#pragma unroll
                for (int r = 0; r < 4; ++r) {
                    int mm = m0 + wm + i * 16 + g * 4 + r;
                    float val = acc[i][j][r] + bb;
                    if (which == 0) qf32[(size_t)mm * 768 + nq + d] = val;
                    qkvbf[((size_t)(which * NH + hcol) * N_TOK + mm) * 64 + d] =
                        f2b(val * scale);
                }
        }
    }
}

// ---------------------------------------------------------------------------
// Rel-pos precompute from UNSCALED fp32 q (qf32[tok][768]). bf16 outputs.
// ---------------------------------------------------------------------------
__global__ __launch_bounds__(256)
void relpos_kernel(const float* __restrict__ qf32,
                   const float* __restrict__ rel_pos_h,
                   const float* __restrict__ rel_pos_w,
                   unsigned short* __restrict__ rh, unsigned short* __restrict__ rw) {
    const int qh = blockIdx.x;
    const int h  = blockIdx.y;
    const int t  = threadIdx.x, tx = t & 15, ty = t >> 4;

    __shared__ float Qt[64][68];
    __shared__ float RH[64][68];
    __shared__ float RW[127][68];

#pragma unroll
    for (int u = 0; u < 4; ++u) {
        int idx = u * 256 + t;
        int row = idx >> 4, c4 = idx & 15;
        *(float4*)&Qt[row][c4 * 4] =
            *(const float4*)&qf32[(size_t)(qh * 64 + row) * 768 + h * HD + c4 * 4];
        *(float4*)&RH[row][c4 * 4] =
            *(const float4*)&rel_pos_h[(size_t)(qh - row + 63) * HD + c4 * 4];
    }
#pragma unroll
    for (int u = 0; u < 8; ++u) {
        int idx = u * 256 + t;
        if (idx < 127 * 16) {
            int row = idx >> 4, c4 = idx & 15;
            *(float4*)&RW[row][c4 * 4] =
                *(const float4*)&rel_pos_w[(size_t)row * HD + c4 * 4];
        }
    }
    __syncthreads();

    float acc1[4][4], acc2[4][4];
#pragma unroll
    for (int i = 0; i < 4; ++i)
#pragma unroll
        for (int j = 0; j < 4; ++j) { acc1[i][j] = 0.f; acc2[i][j] = 0.f; }

    for (int c4 = 0; c4 < 16; ++c4) {
        float4 q4[4], r4[4];
#pragma unroll
        for (int i = 0; i < 4; ++i) q4[i] = *(float4*)&Qt[ty * 4 + i][c4 * 4];
#pragma unroll
        for (int j = 0; j < 4; ++j) r4[j] = *(float4*)&RH[tx * 4 + j][c4 * 4];
#pragma unroll
        for (int i = 0; i < 4; ++i)
#pragma unroll
            for (int j = 0; j < 4; ++j) {
                acc1[i][j] = fmaf(q4[i].x, r4[j].x, acc1[i][j]);
                acc1[i][j] = fmaf(q4[i].y, r4[j].y, acc1[i][j]);
                acc1[i][j] = fmaf(q4[i].z, r4[j].z, acc1[i][j]);
                acc1[i][j] = fmaf(q4[i].w, r4[j].w, acc1[i][j]);
            }
#pragma unroll
        for (int i = 0; i < 4; ++i)
#pragma unroll
            for (int j = 0; j < 4; ++j) {
                float4 w4 = *(float4*)&RW[(ty * 4 + i) - (tx * 4 + j) + 63][c4 * 4];
                acc2[i][j] = fmaf(q4[i].x, w4.x, acc2[i][j]);
                acc2[i][j] = fmaf(q4[i].y, w4.y, acc2[i][j]);
                acc2[i][j] = fmaf(q4[i].z, w4.z, acc2[i][j]);
                acc2[i][j] = fmaf(q4[i].w, w4.w, acc2[i][j]);
            }
    }
#pragma unroll
    for (int i = 0; i < 4; ++i) {
        size_t base = ((size_t)h * N_TOK + qh * 64 + ty * 4 + i) * 64 + tx * 4;
        us4 h4, w4;
        h4.x = f2b(acc1[i][0]); h4.y = f2b(acc1[i][1]);
        h4.z = f2b(acc1[i][2]); h4.w = f2b(acc1[i][3]);
        w4.x = f2b(acc2[i][0]); w4.y = f2b(acc2[i][1]);
        w4.z = f2b(acc2[i][2]); w4.w = f2b(acc2[i][3]);
        *(us4*)&rh[base] = h4;
        *(us4*)&rw[base] = w4;
    }
}

// ---------------------------------------------------------------------------
// Flash attention, bf16 MFMA, head-major bf16 inputs (q pre-scaled).
// R5: permuted-P packed writes (cvt_pk + b64), defer-max (THR=8),
//     register-staged K/V prefetch (T14), XCD swizzle (T1).
// P stored at position p=(key&15)*4+(key>>4); V^T staged in the same order,
// so PV's A/B frags agree on the relabeled contraction index.
// ---------------------------------------------------------------------------
__global__ __launch_bounds__(256, 2)
void attn_mfma(const unsigned short* __restrict__ qkvbf,
               const unsigned short* __restrict__ rh,
               const unsigned short* __restrict__ rw,
               unsigned short* __restrict__ aohi, unsigned short* __restrict__ aolo) {
    int lin = blockIdx.y * 64 + blockIdx.x;       // 768 blocks, %8==0
    lin = (lin & 7) * 96 + (lin >> 3);            // bijective XCD swizzle
    const int qt = lin & 63, h = lin >> 6;
    const int t = threadIdx.x;
    const int lane = t & 63, w = t >> 6;
    const int c15 = lane & 15, g = lane >> 4;

    const unsigned short* qbf = qkvbf + ((size_t)(0 * NH + h)) * N_TOK * 64;
    const unsigned short* kbf = qkvbf + ((size_t)(1 * NH + h)) * N_TOK * 64;
    const unsigned short* vbf = qkvbf + ((size_t)(2 * NH + h)) * N_TOK * 64;

    __shared__ __align__(16) unsigned short Qs[64 * 64];
    __shared__ __align__(16) unsigned short Ks[64 * 64];
    __shared__ __align__(16) unsigned short Vt[64 * 64];   // [d][pos]
    __shared__ __align__(16) unsigned short Ps[4][16 * 64];
    __shared__ __align__(16) float RHs[64 * 68];

    // ---- stage Q (pre-scaled bf16) + RHs (bf16 -> f32)
#pragma unroll
    for (int u = 0; u < 2; ++u) {
        int idx = u * 256 + t;              // 0..511
        int row = idx >> 3, ch = idx & 7;
        bf16x8 v = *(const bf16x8*)&qbf[(size_t)(qt * 64 + row) * 64 + ch * 8];
        int boff = (ch * 16) ^ ((row & 7) << 4);
        *(bf16x8*)((char*)&Qs[row * 64] + boff) = v;
    }
#pragma unroll
    for (int u = 0; u < 4; ++u) {
        int idx = u * 256 + t;
        int row = idx >> 4, c4 = idx & 15;
        us4 v = *(const us4*)&rh[((size_t)h * N_TOK + qt * 64 + row) * 64 + c4 * 4];
        float4 f = make_float4(b2f(v.x), b2f(v.y), b2f(v.z), b2f(v.w));
        *(float4*)&RHs[row * 68 + c4 * 4] = f;
    }
    __syncthreads();

    bf16x8 qf[2];
    {
        int row = w * 16 + c15;
#pragma unroll
        for (int ks = 0; ks < 2; ++ks) {
            int boff = (ks * 64 + g * 16) ^ ((row & 7) << 4);
            qf[ks] = *(bf16x8*)((char*)&Qs[row * 64] + boff);
        }
    }
    float rwreg[4][4];
#pragma unroll
    for (int nt = 0; nt < 4; ++nt)
#pragma unroll
        for (int r = 0; r < 4; ++r)
            rwreg[nt][r] = b2f(rw[((size_t)h * N_TOK + qt * 64 + w * 16 + g * 4 + r) * 64
                                  + nt * 16 + c15]);

    // K/V register prefetch state (T14)
    const int pi = t & 31;
    const int d0 = (t >> 5) * 8;
    const int vm = (pi & 15) + (pi >> 4) * 32;    // key pair (vm, vm+16)
    const int pbase = (pi & 15) * 4 + (pi >> 4) * 2;
    bf16x8 kr0, kr1, vr0, vr1;
    auto LOADKV = [&](int kt) {
        int r0 = t >> 3, ch = t & 7;
        kr0 = *(const bf16x8*)&kbf[(size_t)(kt * 64 + r0) * 64 + ch * 8];
        kr1 = *(const bf16x8*)&kbf[(size_t)(kt * 64 + 32 + r0) * 64 + ch * 8];
        vr0 = *(const bf16x8*)&vbf[(size_t)(kt * 64 + vm) * 64 + d0];
        vr1 = *(const bf16x8*)&vbf[(size_t)(kt * 64 + vm + 16) * 64 + d0];
    };
    LOADKV(0);

    float m_r[4], l_r[4];
    f32x4 acc[4];
#pragma unroll
    for (int r = 0; r < 4; ++r) { m_r[r] = -INFINITY; l_r[r] = 0.f; }
#pragma unroll
    for (int nt = 0; nt < 4; ++nt) acc[nt] = f32x4{0.f, 0.f, 0.f, 0.f};

    for (int kt = 0; kt < 64; ++kt) {
        __syncthreads();                       // prev tile's LDS reads done
        // ---- write staged K (2x ds_write_b128)
        {
            int r0 = t >> 3, ch = t & 7;
            int b0 = (ch * 16) ^ ((r0 & 7) << 4);
            *(bf16x8*)((char*)&Ks[r0 * 64] + b0) = kr0;
            int r1 = 32 + r0;
            int b1 = (ch * 16) ^ ((r1 & 7) << 4);
            *(bf16x8*)((char*)&Ks[r1 * 64] + b1) = kr1;
        }
        // ---- write staged V transposed into permuted key order (8x b32)
#pragma unroll
        for (int j = 0; j < 8; ++j) {
            int d = d0 + j;
            unsigned int pk = (unsigned int)(unsigned short)vr0[j]
                            | ((unsigned int)(unsigned short)vr1[j] << 16);
            int boff = (pbase * 2) ^ ((d & 7) << 4);
            *(unsigned int*)((char*)&Vt[d * 64] + boff) = pk;
        }
        __syncthreads();
        if (kt < 63) LOADKV(kt + 1);           // prefetch hides under compute

        // ---- S = Q K^T
        f32x4 s[4];
#pragma unroll
        for (int nt = 0; nt < 4; ++nt) {
            int krow = nt * 16 + c15;
            int b0 = (g * 16) ^ ((krow & 7) << 4);
            int b1 = (64 + g * 16) ^ ((krow & 7) << 4);
            bf16x8 kf0 = *(bf16x8*)((char*)&Ks[krow * 64] + b0);
            bf16x8 kf1 = *(bf16x8*)((char*)&Ks[krow * 64] + b1);
            f32x4 z = {0.f, 0.f, 0.f, 0.f};
            z = __builtin_amdgcn_mfma_f32_16x16x32_bf16(qf[0], kf0, z, 0, 0, 0);
            z = __builtin_amdgcn_mfma_f32_16x16x32_bf16(qf[1], kf1, z, 0, 0, 0);
            s[nt] = z;
        }
        float rhv[4];
#pragma unroll
        for (int r = 0; r < 4; ++r)
            rhv[r] = RHs[(w * 16 + g * 4 + r) * 68 + kt];
#pragma unroll
        for (int nt = 0; nt < 4; ++nt)
#pragma unroll
            for (int r = 0; r < 4; ++r)
                s[nt][r] += rhv[r] + rwreg[nt][r];

        // ---- online softmax with defer-max (THR=8)
        float mx[4];
#pragma unroll
        for (int r = 0; r < 4; ++r)
            mx[r] = fmaxf(fmaxf(s[0][r], s[1][r]), fmaxf(s[2][r], s[3][r]));
#pragma unroll
        for (int off = 1; off < 16; off <<= 1)
#pragma unroll
            for (int r = 0; r < 4; ++r)
                mx[r] = fmaxf(mx[r], __shfl_xor(mx[r], off, 64));

        bool need = false;
#pragma unroll
        for (int r = 0; r < 4; ++r) need |= (mx[r] > m_r[r] + 8.0f);
        if (__any(need ? 1 : 0)) {
#pragma unroll
            for (int r = 0; r < 4; ++r) {
                float mnew = fmaxf(m_r[r], mx[r]);
                float corr = __expf(m_r[r] - mnew);
                m_r[r] = mnew;
                l_r[r] *= corr;
#pragma unroll
                for (int nt = 0; nt < 4; ++nt)
                    acc[nt][r] *= corr;
            }
        }
        float rsum[4];
#pragma unroll
        for (int r = 0; r < 4; ++r) {
            float su = 0.f;
#pragma unroll
            for (int nt = 0; nt < 4; ++nt) {
                s[nt][r] = __expf(s[nt][r] - m_r[r]);
                su += s[nt][r];
            }
            rsum[r] = su;
        }
#pragma unroll
        for (int off = 1; off < 16; off <<= 1)
#pragma unroll
            for (int r = 0; r < 4; ++r)
                rsum[r] += __shfl_xor(rsum[r], off, 64);
#pragma unroll
        for (int r = 0; r < 4; ++r) l_r[r] += rsum[r];

        // ---- P -> LDS, permuted order: pos = c15*4 + nt (packed b64 writes)
#pragma unroll
        for (int r = 0; r < 4; ++r) {
            int row = g * 4 + r;
            uint2 pv;
            pv.x = pk2(s[0][r], s[1][r]);
            pv.y = pk2(s[2][r], s[3][r]);
            int boff = (c15 * 8) ^ ((row & 7) << 4);
            *(uint2*)((char*)&Ps[w][row * 64] + boff) = pv;
        }

        // ---- O += P V   (frags read in the same permuted position order)
#pragma unroll
        for (int ks = 0; ks < 2; ++ks) {
            int pb = (g * 32 + ks * 16) ^ ((c15 & 7) << 4);
            bf16x8 pf = *(bf16x8*)((char*)&Ps[w][c15 * 64] + pb);
#pragma unroll
            for (int nt = 0; nt < 4; ++nt) {
                int drow = nt * 16 + c15;
                int vb = (g * 32 + ks * 16) ^ ((drow & 7) << 4);
                bf16x8 vf = *(bf16x8*)((char*)&Vt[drow * 64] + vb);
                acc[nt] = __builtin_amdgcn_mfma_f32_16x16x32_bf16(pf, vf, acc[nt], 0, 0, 0);
            }
        }
    }

    // ---- epilogue: ao as split bf16 (A-operand for proj GEMM)
#pragma unroll
    for (int r = 0; r < 4; ++r) {
        float inv = 1.0f / l_r[r];
        size_t orow = (size_t)(qt * 64 + w * 16 + g * 4 + r) * 768 + h * HD;
#pragma unroll
        for (int nt = 0; nt < 4; ++nt) {
            float o = acc[nt][r] * inv;
            unsigned short hi = f2b(o);
            unsigned short lo = f2b(o - b2f(hi));
            aohi[orow + nt * 16 + c15] = hi;
            aolo[orow + nt * 16 + c15] = lo;
        }
    }
}

// ---------------------------------------------------------------------------
extern "C" void kernel_launch(void* const* d_in, const int* in_sizes, int n_in,
                              void* d_out, int out_size, void* d_ws, size_t ws_size,
                              hipStream_t stream) {
    const float* x      = (const float*)d_in[0];
    const float* w_qkv  = (const float*)d_in[1];
    const float* b_qkv  = (const float*)d_in[2];
    const float* w_proj = (const float*)d_in[3];
    const float* b_proj = (const float*)d_in[4];
    const float* rph    = (const float*)d_in[5];
    const float* rpw    = (const float*)d_in[6];
    float* out = (float*)d_out;

    char* p = (char*)d_ws;
    float* qf32           = (float*)p;          p += (size_t)N_TOK * 768 * 4;
    unsigned short* qkvbf = (unsigned short*)p; p += (size_t)3 * NH * N_TOK * 64 * 2;
    unsigned short* rhbf  = (unsigned short*)p; p += (size_t)NH * N_TOK * 64 * 2;
    unsigned short* rwbf  = (unsigned short*)p; p += (size_t)NH * N_TOK * 64 * 2;
    unsigned short* xhi   = (unsigned short*)p; p += (size_t)N_TOK * 768 * 2;
    unsigned short* xlo   = (unsigned short*)p; p += (size_t)N_TOK * 768 * 2;
    unsigned short* wqThi = (unsigned short*)p; p += (size_t)2304 * 768 * 2;
    unsigned short* wqTlo = (unsigned short*)p; p += (size_t)2304 * 768 * 2;
    unsigned short* wpThi = (unsigned short*)p; p += (size_t)768 * 768 * 2;
    unsigned short* wpTlo = (unsigned short*)p; p += (size_t)768 * 768 * 2;
    unsigned short* aohi = xhi;   // alias: x consumed before attn writes ao
    unsigned short* aolo = xlo;

    conv_split<<<1024, 256, 0, stream>>>(x, xhi, xlo, N_TOK * 768 / 4);
    transpose_split<<<dim3(36, 12), 256, 0, stream>>>(w_qkv, wqThi, wqTlo, 768, 2304);
    transpose_split<<<dim3(12, 12), 256, 0, stream>>>(w_proj, wpThi, wpTlo, 768, 768);

    gemm_split<N_TOK, 2304, 768, 1><<<dim3(18, 32), 256, 0, stream>>>(
        xhi, xlo, wqThi, wqTlo, b_qkv, nullptr, qf32, qkvbf);

    relpos_kernel<<<dim3(64, NH), 256, 0, stream>>>(qf32, rph, rpw, rhbf, rwbf);

    attn_mfma<<<dim3(64, NH), 256, 0, stream>>>(qkvbf, rhbf, rwbf, aohi, aolo);

    gemm_split<N_TOK, 768, 768, 0><<<dim3(6, 32), 256, 0, stream>>>(
        aohi, aolo, wpThi, wpTlo, b_proj, out, nullptr, nullptr);
}

// Round 6
// 330.785 us; speedup vs baseline: 6.0652x; 1.1114x over previous
//
#include <hip/hip_runtime.h>
#include <math.h>

#define N_TOK 4096
#define DIM   768
#define NH    12
#define HD    64

typedef __attribute__((ext_vector_type(8))) short bf16x8;
typedef __attribute__((ext_vector_type(4))) float f32x4;
typedef __attribute__((ext_vector_type(4))) unsigned short us4;

__device__ inline unsigned short f2b(float f) {   // fp32 -> bf16 RNE
    union { float f; unsigned int u; } v; v.f = f;
    unsigned int r = v.u + 0x7FFFu + ((v.u >> 16) & 1u);
    return (unsigned short)(r >> 16);
}
__device__ inline float b2f(unsigned short u) {
    union { unsigned int u; float f; } v; v.u = ((unsigned int)u) << 16;
    return v.f;
}
__device__ inline unsigned int pk2(float lo, float hi) {   // 2x f32 -> packed bf16 RNE
    unsigned int u;
    asm("v_cvt_pk_bf16_f32 %0, %1, %2" : "=v"(u) : "v"(lo), "v"(hi));
    return u;
}
__device__ inline void gload16(const void* g, void* l) {
    __builtin_amdgcn_global_load_lds(
        (const __attribute__((address_space(1))) unsigned int*)g,
        (__attribute__((address_space(3))) unsigned int*)l, 16, 0, 0);
}

// ---------------------------------------------------------------------------
// fp32 -> (hi, lo) bf16 split, elementwise.  n4 = elems/4.
// ---------------------------------------------------------------------------
__global__ __launch_bounds__(256)
void conv_split(const float* __restrict__ X, unsigned short* __restrict__ hi,
                unsigned short* __restrict__ lo, int n4) {
    int i = blockIdx.x * 256 + threadIdx.x;
    int stride = gridDim.x * 256;
    for (; i < n4; i += stride) {
        float4 v = ((const float4*)X)[i];
        us4 h, l;
        h.x = f2b(v.x); l.x = f2b(v.x - b2f(h.x));
        h.y = f2b(v.y); l.y = f2b(v.y - b2f(h.y));
        h.z = f2b(v.z); l.z = f2b(v.z - b2f(h.z));
        h.w = f2b(v.w); l.w = f2b(v.w - b2f(h.w));
        ((us4*)hi)[i] = h;
        ((us4*)lo)[i] = l;
    }
}

// ---------------------------------------------------------------------------
// W[K][N] fp32 -> T[N][K] split bf16 (hi, lo). 64x64 tiles.
// ---------------------------------------------------------------------------
__global__ __launch_bounds__(256)
void transpose_split(const float* __restrict__ W, unsigned short* __restrict__ Thi,
                     unsigned short* __restrict__ Tlo, int K, int N) {
    __shared__ float tile[64][65];
    const int t = threadIdx.x;
    const int k0 = blockIdx.y * 64, n0 = blockIdx.x * 64;
#pragma unroll
    for (int u = 0; u < 4; ++u) {
        int idx = u * 256 + t;
        int r = idx >> 4, c4 = idx & 15;
        float4 v = *(const float4*)&W[(size_t)(k0 + r) * N + n0 + c4 * 4];
        tile[r][c4 * 4 + 0] = v.x; tile[r][c4 * 4 + 1] = v.y;
        tile[r][c4 * 4 + 2] = v.z; tile[r][c4 * 4 + 3] = v.w;
    }
    __syncthreads();
#pragma unroll
    for (int u = 0; u < 4; ++u) {
        int idx = u * 256 + t;
        int col = idx >> 4, c4 = idx & 15;
        float a0 = tile[c4 * 4 + 0][col], a1 = tile[c4 * 4 + 1][col];
        float a2 = tile[c4 * 4 + 2][col], a3 = tile[c4 * 4 + 3][col];
        us4 h, l;
        h.x = f2b(a0); l.x = f2b(a0 - b2f(h.x));
        h.y = f2b(a1); l.y = f2b(a1 - b2f(h.y));
        h.z = f2b(a2); l.z = f2b(a2 - b2f(h.z));
        h.w = f2b(a3); l.w = f2b(a3 - b2f(h.w));
        size_t o = (size_t)(n0 + col) * K + k0 + c4 * 4;
        *(us4*)&Thi[o] = h;
        *(us4*)&Tlo[o] = l;
    }
}

// ---------------------------------------------------------------------------
// Split-bf16 MFMA GEMM, BM=128 BN=96 BK=32. 4 waves, wave = 64x48.
// Grids: qkv (24,32)=768 blks = 3.0/CU; proj (8,32)=256 = 1.0/CU (no tail).
// MODE 0: Cout[M][N] fp32 + bias.
// MODE 1: qkvbf[(which*NH+head)][tok][64] bf16, q (which==0) pre-scaled 0.125.
// ---------------------------------------------------------------------------
template<int M, int N, int K, int MODE>
__global__ __launch_bounds__(256)
void gemm_split(const unsigned short* __restrict__ Ahi, const unsigned short* __restrict__ Alo,
                const unsigned short* __restrict__ BThi, const unsigned short* __restrict__ BTlo,
                const float* __restrict__ bias, float* __restrict__ Cout,
                unsigned short* __restrict__ qkvbf) {
    __shared__ __align__(16) char smem[28672];   // Ahi 8K | Alo 8K | Bhi 6K | Blo 6K
    const int t = threadIdx.x, lane = t & 63, w = t >> 6;
    const int c15 = lane & 15, g = lane >> 4;
    const int nwg = gridDim.x * gridDim.y;
    int lin = blockIdx.y * gridDim.x + blockIdx.x;
    lin = (lin & 7) * (nwg >> 3) + (lin >> 3);   // bijective XCD swizzle (nwg%8==0)
    const int m0 = (lin / gridDim.x) * 128, n0 = (lin % gridDim.x) * 96;
    const int wm = (w >> 1) * 64, wn = (w & 1) * 48;

    f32x4 acc[4][3];
#pragma unroll
    for (int i = 0; i < 4; ++i)
#pragma unroll
        for (int j = 0; j < 3; ++j) acc[i][j] = f32x4{0.f, 0.f, 0.f, 0.f};

    for (int k0 = 0; k0 < K; k0 += 32) {
        __syncthreads();
#pragma unroll
        for (int p = 0; p < 2; ++p) {
            int off = p * 4096 + w * 1024 + lane * 16;
            int row = off >> 6;
            int gs  = ((off >> 4) & 3) ^ (row & 3);
            size_t ae = (size_t)(m0 + row) * K + k0 + gs * 8;
            char* dstA = smem + off - lane * 16;          // wave-uniform base
            gload16(Ahi + ae, dstA);
            gload16(Alo + ae, dstA + 8192);
            if (off < 6144) {                              // B: 96 rows only
                size_t be = (size_t)(n0 + row) * K + k0 + gs * 8;
                char* dstB = smem + 16384 + off - lane * 16;
                gload16(BThi + be, dstB);
                gload16(BTlo + be, dstB + 6144);
            }
        }
        __syncthreads();

        bf16x8 ah[4], al[4], bh[3], bl[3];
#pragma unroll
        for (int i = 0; i < 4; ++i) {
            int ra = wm + i * 16 + c15;
            int boa = ra * 64 + ((g ^ (ra & 3)) << 4);
            ah[i] = *(const bf16x8*)(smem + boa);
            al[i] = *(const bf16x8*)(smem + 8192 + boa);
        }
#pragma unroll
        for (int j = 0; j < 3; ++j) {
            int rb = wn + j * 16 + c15;
            int bob = rb * 64 + ((g ^ (rb & 3)) << 4);
            bh[j] = *(const bf16x8*)(smem + 16384 + bob);
            bl[j] = *(const bf16x8*)(smem + 22528 + bob);
        }
        __builtin_amdgcn_s_setprio(1);
#pragma unroll
        for (int i = 0; i < 4; ++i)
#pragma unroll
            for (int j = 0; j < 3; ++j) {
                acc[i][j] = __builtin_amdgcn_mfma_f32_16x16x32_bf16(ah[i], bh[j], acc[i][j], 0, 0, 0);
                acc[i][j] = __builtin_amdgcn_mfma_f32_16x16x32_bf16(ah[i], bl[j], acc[i][j], 0, 0, 0);
                acc[i][j] = __builtin_amdgcn_mfma_f32_16x16x32_bf16(al[i], bh[j], acc[i][j], 0, 0, 0);
            }
        __builtin_amdgcn_s_setprio(0);
    }

    const int nq = n0 + wn;
    if (MODE == 0) {
#pragma unroll
        for (int j = 0; j < 3; ++j) {
            float bb = bias[nq + j * 16 + c15];
#pragma unroll
            for (int i = 0; i < 4; ++i)
#pragma unroll
                for (int r = 0; r < 4; ++r) {
                    int mm = m0 + wm + i * 16 + g * 4 + r;
                    Cout[(size_t)mm * N + nq + j * 16 + c15] = acc[i][j][r] + bb;
                }
        }
    } else {
        const int which = nq / 768;          // uniform: 96 | 768
        const float scale = (which == 0) ? 0.125f : 1.0f;
#pragma unroll
        for (int j = 0; j < 3; ++j) {
            int colg = nq + j * 16;
            int head = (colg % 768) >> 6;    // uniform per j
            int dbase = colg & 63;
            float bb = bias[colg + c15];
#pragma unroll
            for (int i = 0; i < 4; ++i)
#pragma unroll
                for (int r = 0; r < 4; ++r) {
                    int mm = m0 + wm + i * 16 + g * 4 + r;
                    float val = acc[i][j][r] + bb;
                    qkvbf[((size_t)(which * NH + head) * N_TOK + mm) * 64 + dbase + c15] =
                        f2b(val * scale);
                }
        }
    }
}

// ---------------------------------------------------------------------------
// rel_w precompute only (rel_h fused into attn). Reads bf16 q (scaled 0.125),
// compensates x8. rw[h][tok][64] bf16.
// ---------------------------------------------------------------------------
__global__ __launch_bounds__(256)
void relpos_rw(const unsigned short* __restrict__ qkvbf,
               const float* __restrict__ rel_pos_w,
               unsigned short* __restrict__ rw) {
    const int qh = blockIdx.x;
    const int h  = blockIdx.y;
    const int t  = threadIdx.x, tx = t & 15, ty = t >> 4;
    const unsigned short* qbf = qkvbf + (size_t)h * N_TOK * 64;

    __shared__ float Qt[64][68];
    __shared__ float RW[127][68];

#pragma unroll
    for (int u = 0; u < 2; ++u) {
        int idx = u * 256 + t;              // 0..511
        int row = idx >> 3, ch = idx & 7;
        bf16x8 v = *(const bf16x8*)&qbf[(size_t)(qh * 64 + row) * 64 + ch * 8];
#pragma unroll
        for (int j = 0; j < 8; ++j)
            Qt[row][ch * 8 + j] = b2f((unsigned short)v[j]) * 8.0f;   // un-scale
    }
#pragma unroll
    for (int u = 0; u < 8; ++u) {
        int idx = u * 256 + t;
        if (idx < 127 * 16) {
            int row = idx >> 4, c4 = idx & 15;
            *(float4*)&RW[row][c4 * 4] =
                *(const float4*)&rel_pos_w[(size_t)row * HD + c4 * 4];
        }
    }
    __syncthreads();

    float acc2[4][4];
#pragma unroll
    for (int i = 0; i < 4; ++i)
#pragma unroll
        for (int j = 0; j < 4; ++j) acc2[i][j] = 0.f;

    for (int c4 = 0; c4 < 16; ++c4) {
        float4 q4[4];
#pragma unroll
        for (int i = 0; i < 4; ++i) q4[i] = *(float4*)&Qt[ty * 4 + i][c4 * 4];
#pragma unroll
        for (int i = 0; i < 4; ++i)
#pragma unroll
            for (int j = 0; j < 4; ++j) {
                float4 w4 = *(float4*)&RW[(ty * 4 + i) - (tx * 4 + j) + 63][c4 * 4];
                acc2[i][j] = fmaf(q4[i].x, w4.x, acc2[i][j]);
                acc2[i][j] = fmaf(q4[i].y, w4.y, acc2[i][j]);
                acc2[i][j] = fmaf(q4[i].z, w4.z, acc2[i][j]);
                acc2[i][j] = fmaf(q4[i].w, w4.w, acc2[i][j]);
            }
    }
#pragma unroll
    for (int i = 0; i < 4; ++i) {
        size_t base = ((size_t)h * N_TOK + qh * 64 + ty * 4 + i) * 64 + tx * 4;
        us4 w4;
        w4.x = f2b(acc2[i][0]); w4.y = f2b(acc2[i][1]);
        w4.z = f2b(acc2[i][2]); w4.w = f2b(acc2[i][3]);
        *(us4*)&rw[base] = w4;
    }
}

// ---------------------------------------------------------------------------
// Flash attention, bf16 MFMA. R6: K/V LDS double-buffer (1 barrier/tile),
// rel_h fused via MFMA + shfl broadcast, P-write h(row)-swizzle, setprio,
// 3 blocks/CU. LDS 48 KB.
// ---------------------------------------------------------------------------
__global__ __launch_bounds__(256, 3)
void attn_mfma(const unsigned short* __restrict__ qkvbf,
               const unsigned short* __restrict__ rw,
               const float* __restrict__ rel_pos_h,
               unsigned short* __restrict__ aohi, unsigned short* __restrict__ aolo) {
    int lin = blockIdx.y * 64 + blockIdx.x;       // 768 blocks
    lin = (lin & 7) * 96 + (lin >> 3);            // bijective XCD swizzle
    const int qt = lin & 63, h = lin >> 6;
    const int t = threadIdx.x;
    const int lane = t & 63, w = t >> 6;
    const int c15 = lane & 15, g = lane >> 4;

    const unsigned short* qbf = qkvbf + ((size_t)(0 * NH + h)) * N_TOK * 64;
    const unsigned short* kbf = qkvbf + ((size_t)(1 * NH + h)) * N_TOK * 64;
    const unsigned short* vbf = qkvbf + ((size_t)(2 * NH + h)) * N_TOK * 64;

    __shared__ __align__(16) unsigned short Qs[64 * 64];
    __shared__ __align__(16) unsigned short Ks[2][64 * 64];   // [1] hosts RH8 at init
    __shared__ __align__(16) unsigned short Vt[2][64 * 64];
    __shared__ __align__(16) unsigned short Ps[4][16 * 64];

    // ---- K/V register-stage helpers (T14)
    const int pi = t & 31;
    const int d0 = (t >> 5) * 8;
    const int vm = (pi & 15) + (pi >> 4) * 32;    // key pair (vm, vm+16)
    const int pbase = (pi & 15) * 4 + (pi >> 4) * 2;
    const int kr_row = t >> 3, kr_ch = t & 7;
    bf16x8 kr0, kr1, vr0, vr1;
    auto LOADKV = [&](int kt) {
        kr0 = *(const bf16x8*)&kbf[(size_t)(kt * 64 + kr_row) * 64 + kr_ch * 8];
        kr1 = *(const bf16x8*)&kbf[(size_t)(kt * 64 + 32 + kr_row) * 64 + kr_ch * 8];
        vr0 = *(const bf16x8*)&vbf[(size_t)(kt * 64 + vm) * 64 + d0];
        vr1 = *(const bf16x8*)&vbf[(size_t)(kt * 64 + vm + 16) * 64 + d0];
    };
    auto WRITEKV = [&](int buf) {
        int b0 = (kr_ch * 16) ^ ((kr_row & 7) << 4);
        *(bf16x8*)((char*)&Ks[buf][kr_row * 64] + b0) = kr0;
        int r1 = 32 + kr_row;
        int b1 = (kr_ch * 16) ^ ((r1 & 7) << 4);
        *(bf16x8*)((char*)&Ks[buf][r1 * 64] + b1) = kr1;
#pragma unroll
        for (int j = 0; j < 8; ++j) {
            int d = d0 + j;
            unsigned int pk = (unsigned int)(unsigned short)vr0[j]
                            | ((unsigned int)(unsigned short)vr1[j] << 16);
            int boff = (pbase * 2) ^ ((d & 7) << 4);
            *(unsigned int*)((char*)&Vt[buf][d * 64] + boff) = pk;
        }
    };

    // ---- init: stage Q, RH8 (=8*rel_pos_h rows, bf16) into Ks[1], load t=0
#pragma unroll
    for (int u = 0; u < 2; ++u) {
        int idx = u * 256 + t;              // 0..511
        int row = idx >> 3, ch = idx & 7;
        bf16x8 v = *(const bf16x8*)&qbf[(size_t)(qt * 64 + row) * 64 + ch * 8];
        int boff = (ch * 16) ^ ((row & 7) << 4);
        *(bf16x8*)((char*)&Qs[row * 64] + boff) = v;
    }
#pragma unroll
    for (int u = 0; u < 4; ++u) {
        int idx = u * 256 + t;              // 0..1023
        int row = idx >> 4, c4 = idx & 15;  // row = kt index
        float4 v = *(const float4*)&rel_pos_h[(size_t)(qt - row + 63) * HD + c4 * 4];
        us4 p = {f2b(v.x * 8.f), f2b(v.y * 8.f), f2b(v.z * 8.f), f2b(v.w * 8.f)};
        int boff = (c4 * 8) ^ ((row & 7) << 4);
        *(us4*)((char*)&Ks[1][row * 64] + boff) = p;
    }
    LOADKV(0);
    __syncthreads();

    WRITEKV(0);
    bf16x8 qf[2];
    {
        int row = w * 16 + c15;
#pragma unroll
        for (int ks = 0; ks < 2; ++ks) {
            int boff = (ks * 64 + g * 16) ^ ((row & 7) << 4);
            qf[ks] = *(bf16x8*)((char*)&Qs[row * 64] + boff);
        }
    }
    // rhacc = Q_scaled @ RH8^T  (net = unscaled q . rel_pos_h)
    f32x4 rhacc[4];
#pragma unroll
    for (int nt = 0; nt < 4; ++nt) {
        int krow = nt * 16 + c15;
        int b0 = (g * 16) ^ ((krow & 7) << 4);
        int b1 = (64 + g * 16) ^ ((krow & 7) << 4);
        bf16x8 rf0 = *(bf16x8*)((char*)&Ks[1][krow * 64] + b0);
        bf16x8 rf1 = *(bf16x8*)((char*)&Ks[1][krow * 64] + b1);
        f32x4 z = {0.f, 0.f, 0.f, 0.f};
        z = __builtin_amdgcn_mfma_f32_16x16x32_bf16(qf[0], rf0, z, 0, 0, 0);
        z = __builtin_amdgcn_mfma_f32_16x16x32_bf16(qf[1], rf1, z, 0, 0, 0);
        rhacc[nt] = z;
    }
    LOADKV(1);

    float rwreg[4][4];
#pragma unroll
    for (int nt = 0; nt < 4; ++nt)
#pragma unroll
        for (int r = 0; r < 4; ++r)
            rwreg[nt][r] = b2f(rw[((size_t)h * N_TOK + qt * 64 + w * 16 + g * 4 + r) * 64
                                  + nt * 16 + c15]);

    float m_r[4], l_r[4];
    f32x4 acc[4];
#pragma unroll
    for (int r = 0; r < 4; ++r) { m_r[r] = -INFINITY; l_r[r] = 0.f; }
#pragma unroll
    for (int nt = 0; nt < 4; ++nt) acc[nt] = f32x4{0.f, 0.f, 0.f, 0.f};

    __syncthreads();   // Ks[0]/Vt[0] visible; rhacc reads of Ks[1] complete

#pragma unroll
    for (int kt4 = 0; kt4 < 4; ++kt4) {
#pragma unroll 2
        for (int kti = 0; kti < 16; ++kti) {
            const int kt = kt4 * 16 + kti;
            const int cur = kt & 1, nxt = cur ^ 1;
            // ---- write next tile from regs; issue load for kt+2
            if (kt < 63) WRITEKV(nxt);
            if (kt < 62) LOADKV(kt + 2);

            // ---- S = Q K^T
            f32x4 s[4];
            __builtin_amdgcn_s_setprio(1);
#pragma unroll
            for (int nt = 0; nt < 4; ++nt) {
                int krow = nt * 16 + c15;
                int b0 = (g * 16) ^ ((krow & 7) << 4);
                int b1 = (64 + g * 16) ^ ((krow & 7) << 4);
                bf16x8 kf0 = *(bf16x8*)((char*)&Ks[cur][krow * 64] + b0);
                bf16x8 kf1 = *(bf16x8*)((char*)&Ks[cur][krow * 64] + b1);
                f32x4 z = {0.f, 0.f, 0.f, 0.f};
                z = __builtin_amdgcn_mfma_f32_16x16x32_bf16(qf[0], kf0, z, 0, 0, 0);
                z = __builtin_amdgcn_mfma_f32_16x16x32_bf16(qf[1], kf1, z, 0, 0, 0);
                s[nt] = z;
            }
            __builtin_amdgcn_s_setprio(0);

            // ---- rel-pos: rh via shfl from rhacc (kt4 static), rw from regs
            float rhv[4];
#pragma unroll
            for (int r = 0; r < 4; ++r)
                rhv[r] = __shfl(rhacc[kt4][r], (lane & 48) | kti, 64);
#pragma unroll
            for (int nt = 0; nt < 4; ++nt)
#pragma unroll
                for (int r = 0; r < 4; ++r)
                    s[nt][r] += rhv[r] + rwreg[nt][r];

            // ---- online softmax with defer-max (THR=8)
            float mx[4];
#pragma unroll
            for (int r = 0; r < 4; ++r)
                mx[r] = fmaxf(fmaxf(s[0][r], s[1][r]), fmaxf(s[2][r], s[3][r]));
#pragma unroll
            for (int off = 1; off < 16; off <<= 1)
#pragma unroll
                for (int r = 0; r < 4; ++r)
                    mx[r] = fmaxf(mx[r], __shfl_xor(mx[r], off, 64));

            bool need = false;
#pragma unroll
            for (int r = 0; r < 4; ++r) need |= (mx[r] > m_r[r] + 8.0f);
            if (__any(need ? 1 : 0)) {
#pragma unroll
                for (int r = 0; r < 4; ++r) {
                    float mnew = fmaxf(m_r[r], mx[r]);
                    float corr = __expf(m_r[r] - mnew);
                    m_r[r] = mnew;
                    l_r[r] *= corr;
#pragma unroll
                    for (int nt = 0; nt < 4; ++nt)
                        acc[nt][r] *= corr;
                }
            }
            float rsum[4];
#pragma unroll
            for (int r = 0; r < 4; ++r) {
                float su = 0.f;
#pragma unroll
                for (int nt = 0; nt < 4; ++nt) {
                    s[nt][r] = __expf(s[nt][r] - m_r[r]);
                    su += s[nt][r];
                }
                rsum[r] = su;
            }
#pragma unroll
            for (int off = 1; off < 16; off <<= 1)
#pragma unroll
                for (int r = 0; r < 4; ++r)
                    rsum[r] += __shfl_xor(rsum[r], off, 64);
#pragma unroll
            for (int r = 0; r < 4; ++r) l_r[r] += rsum[r];

            // ---- P -> LDS (permuted pos = (key&15)*4 + key>>4), h(row) swizzle
#pragma unroll
            for (int r = 0; r < 4; ++r) {
                int row = g * 4 + r;
                int hr = (row ^ (row >> 1)) & 7;
                uint2 pv;
                pv.x = pk2(s[0][r], s[1][r]);
                pv.y = pk2(s[2][r], s[3][r]);
                int boff = (c15 * 8) ^ (hr << 4);
                *(uint2*)((char*)&Ps[w][row * 64] + boff) = pv;
            }

            // ---- O += P V
            const int hc = (c15 ^ (c15 >> 1)) & 7;
            __builtin_amdgcn_s_setprio(1);
#pragma unroll
            for (int ks = 0; ks < 2; ++ks) {
                int pb = (g * 32 + ks * 16) ^ (hc << 4);
                bf16x8 pf = *(bf16x8*)((char*)&Ps[w][c15 * 64] + pb);
#pragma unroll
                for (int nt = 0; nt < 4; ++nt) {
                    int drow = nt * 16 + c15;
                    int vb = (g * 32 + ks * 16) ^ ((drow & 7) << 4);
                    bf16x8 vf = *(bf16x8*)((char*)&Vt[cur][drow * 64] + vb);
                    acc[nt] = __builtin_amdgcn_mfma_f32_16x16x32_bf16(pf, vf, acc[nt], 0, 0, 0);
                }
            }
            __builtin_amdgcn_s_setprio(0);

            __syncthreads();   // all waves done with buf[cur] before next overwrite
        }
    }

    // ---- epilogue: ao as split bf16 (A-operand for proj GEMM)
#pragma unroll
    for (int r = 0; r < 4; ++r) {
        float inv = 1.0f / l_r[r];
        size_t orow = (size_t)(qt * 64 + w * 16 + g * 4 + r) * 768 + h * HD;
#pragma unroll
        for (int nt = 0; nt < 4; ++nt) {
            float o = acc[nt][r] * inv;
            unsigned short hi = f2b(o);
            unsigned short lo = f2b(o - b2f(hi));
            aohi[orow + nt * 16 + c15] = hi;
            aolo[orow + nt * 16 + c15] = lo;
        }
    }
}

// ---------------------------------------------------------------------------
extern "C" void kernel_launch(void* const* d_in, const int* in_sizes, int n_in,
                              void* d_out, int out_size, void* d_ws, size_t ws_size,
                              hipStream_t stream) {
    const float* x      = (const float*)d_in[0];
    const float* w_qkv  = (const float*)d_in[1];
    const float* b_qkv  = (const float*)d_in[2];
    const float* w_proj = (const float*)d_in[3];
    const float* b_proj = (const float*)d_in[4];
    const float* rph    = (const float*)d_in[5];
    const float* rpw    = (const float*)d_in[6];
    float* out = (float*)d_out;

    char* p = (char*)d_ws;
    unsigned short* qkvbf = (unsigned short*)p; p += (size_t)3 * NH * N_TOK * 64 * 2;
    unsigned short* rwbf  = (unsigned short*)p; p += (size_t)NH * N_TOK * 64 * 2;
    unsigned short* xhi   = (unsigned short*)p; p += (size_t)N_TOK * 768 * 2;
    unsigned short* xlo   = (unsigned short*)p; p += (size_t)N_TOK * 768 * 2;
    unsigned short* wqThi = (unsigned short*)p; p += (size_t)2304 * 768 * 2;
    unsigned short* wqTlo = (unsigned short*)p; p += (size_t)2304 * 768 * 2;
    unsigned short* wpThi = (unsigned short*)p; p += (size_t)768 * 768 * 2;
    unsigned short* wpTlo = (unsigned short*)p; p += (size_t)768 * 768 * 2;
    unsigned short* aohi = xhi;   // alias: x consumed before attn writes ao
    unsigned short* aolo = xlo;

    conv_split<<<1024, 256, 0, stream>>>(x, xhi, xlo, N_TOK * 768 / 4);
    transpose_split<<<dim3(36, 12), 256, 0, stream>>>(w_qkv, wqThi, wqTlo, 768, 2304);
    transpose_split<<<dim3(12, 12), 256, 0, stream>>>(w_proj, wpThi, wpTlo, 768, 768);

    gemm_split<N_TOK, 2304, 768, 1><<<dim3(24, 32), 256, 0, stream>>>(
        xhi, xlo, wqThi, wqTlo, b_qkv, nullptr, qkvbf);

    relpos_rw<<<dim3(64, NH), 256, 0, stream>>>(qkvbf, rpw, rwbf);

    attn_mfma<<<dim3(64, NH), 256, 0, stream>>>(qkvbf, rwbf, rph, aohi, aolo);

    gemm_split<N_TOK, 768, 768, 0><<<dim3(8, 32), 256, 0, stream>>>(
        aohi, aolo, wpThi, wpTlo, b_proj, out, nullptr);
}

// Round 7
// 301.792 us; speedup vs baseline: 6.6479x; 1.0961x over previous
//
#include <hip/hip_runtime.h>
#include <math.h>

#define N_TOK 4096
#define DIM   768
#define NH    12
#define HD    64

typedef __attribute__((ext_vector_type(8))) short bf16x8;
typedef __attribute__((ext_vector_type(4))) float f32x4;
typedef __attribute__((ext_vector_type(4))) unsigned short us4;

__device__ inline unsigned short f2b(float f) {   // fp32 -> bf16 RNE
    union { float f; unsigned int u; } v; v.f = f;
    unsigned int r = v.u + 0x7FFFu + ((v.u >> 16) & 1u);
    return (unsigned short)(r >> 16);
}
__device__ inline float b2f(unsigned short u) {
    union { unsigned int u; float f; } v; v.u = ((unsigned int)u) << 16;
    return v.f;
}
__device__ inline unsigned int pk2(float lo, float hi) {   // 2x f32 -> packed bf16 RNE
    unsigned int u;
    asm("v_cvt_pk_bf16_f32 %0, %1, %2" : "=v"(u) : "v"(lo), "v"(hi));
    return u;
}
__device__ inline void gload16(const void* g, void* l) {
    __builtin_amdgcn_global_load_lds(
        (const __attribute__((address_space(1))) unsigned int*)g,
        (__attribute__((address_space(3))) unsigned int*)l, 16, 0, 0);
}

// ---------------------------------------------------------------------------
// fp32 -> (hi, lo) bf16 split, elementwise.  n4 = elems/4.
// ---------------------------------------------------------------------------
__global__ __launch_bounds__(256)
void conv_split(const float* __restrict__ X, unsigned short* __restrict__ hi,
                unsigned short* __restrict__ lo, int n4) {
    int i = blockIdx.x * 256 + threadIdx.x;
    int stride = gridDim.x * 256;
    for (; i < n4; i += stride) {
        float4 v = ((const float4*)X)[i];
        us4 h, l;
        h.x = f2b(v.x); l.x = f2b(v.x - b2f(h.x));
        h.y = f2b(v.y); l.y = f2b(v.y - b2f(h.y));
        h.z = f2b(v.z); l.z = f2b(v.z - b2f(h.z));
        h.w = f2b(v.w); l.w = f2b(v.w - b2f(h.w));
        ((us4*)hi)[i] = h;
        ((us4*)lo)[i] = l;
    }
}

// ---------------------------------------------------------------------------
// W[K][N] fp32 -> T[N][K] split bf16 (hi, lo). 64x64 tiles.
// ---------------------------------------------------------------------------
__global__ __launch_bounds__(256)
void transpose_split(const float* __restrict__ W, unsigned short* __restrict__ Thi,
                     unsigned short* __restrict__ Tlo, int K, int N) {
    __shared__ float tile[64][65];
    const int t = threadIdx.x;
    const int k0 = blockIdx.y * 64, n0 = blockIdx.x * 64;
#pragma unroll
    for (int u = 0; u < 4; ++u) {
        int idx = u * 256 + t;
        int r = idx >> 4, c4 = idx & 15;
        float4 v = *(const float4*)&W[(size_t)(k0 + r) * N + n0 + c4 * 4];
        tile[r][c4 * 4 + 0] = v.x; tile[r][c4 * 4 + 1] = v.y;
        tile[r][c4 * 4 + 2] = v.z; tile[r][c4 * 4 + 3] = v.w;
    }
    __syncthreads();
#pragma unroll
    for (int u = 0; u < 4; ++u) {
        int idx = u * 256 + t;
        int col = idx >> 4, c4 = idx & 15;
        float a0 = tile[c4 * 4 + 0][col], a1 = tile[c4 * 4 + 1][col];
        float a2 = tile[c4 * 4 + 2][col], a3 = tile[c4 * 4 + 3][col];
        us4 h, l;
        h.x = f2b(a0); l.x = f2b(a0 - b2f(h.x));
        h.y = f2b(a1); l.y = f2b(a1 - b2f(h.y));
        h.z = f2b(a2); l.z = f2b(a2 - b2f(h.z));
        h.w = f2b(a3); l.w = f2b(a3 - b2f(h.w));
        size_t o = (size_t)(n0 + col) * K + k0 + c4 * 4;
        *(us4*)&Thi[o] = h;
        *(us4*)&Tlo[o] = l;
    }
}

// ---------------------------------------------------------------------------
// Split-bf16 MFMA GEMM, BM=128 BN=96 BK=32. 4 waves, wave = 64x48.
// MODE 0: Cout[M][N] fp32 + bias.
// MODE 1: qkvbf[(which*NH+head)][tok][64] bf16, q pre-scaled 0.125*log2(e).
// ---------------------------------------------------------------------------
template<int M, int N, int K, int MODE>
__global__ __launch_bounds__(256)
void gemm_split(const unsigned short* __restrict__ Ahi, const unsigned short* __restrict__ Alo,
                const unsigned short* __restrict__ BThi, const unsigned short* __restrict__ BTlo,
                const float* __restrict__ bias, float* __restrict__ Cout,
                unsigned short* __restrict__ qkvbf) {
    __shared__ __align__(16) char smem[28672];   // Ahi 8K | Alo 8K | Bhi 6K | Blo 6K
    const int t = threadIdx.x, lane = t & 63, w = t >> 6;
    const int c15 = lane & 15, g = lane >> 4;
    const int nwg = gridDim.x * gridDim.y;
    int lin = blockIdx.y * gridDim.x + blockIdx.x;
    lin = (lin & 7) * (nwg >> 3) + (lin >> 3);   // bijective XCD swizzle (nwg%8==0)
    const int m0 = (lin / gridDim.x) * 128, n0 = (lin % gridDim.x) * 96;
    const int wm = (w >> 1) * 64, wn = (w & 1) * 48;

    f32x4 acc[4][3];
#pragma unroll
    for (int i = 0; i < 4; ++i)
#pragma unroll
        for (int j = 0; j < 3; ++j) acc[i][j] = f32x4{0.f, 0.f, 0.f, 0.f};

    for (int k0 = 0; k0 < K; k0 += 32) {
        __syncthreads();
#pragma unroll
        for (int p = 0; p < 2; ++p) {
            int off = p * 4096 + w * 1024 + lane * 16;
            int row = off >> 6;
            int gs  = ((off >> 4) & 3) ^ (row & 3);
            size_t ae = (size_t)(m0 + row) * K + k0 + gs * 8;
            char* dstA = smem + off - lane * 16;          // wave-uniform base
            gload16(Ahi + ae, dstA);
            gload16(Alo + ae, dstA + 8192);
            if (off < 6144) {                              // B: 96 rows only
                size_t be = (size_t)(n0 + row) * K + k0 + gs * 8;
                char* dstB = smem + 16384 + off - lane * 16;
                gload16(BThi + be, dstB);
                gload16(BTlo + be, dstB + 6144);
            }
        }
        __syncthreads();

        bf16x8 ah[4], al[4], bh[3], bl[3];
#pragma unroll
        for (int i = 0; i < 4; ++i) {
            int ra = wm + i * 16 + c15;
            int boa = ra * 64 + ((g ^ (ra & 3)) << 4);
            ah[i] = *(const bf16x8*)(smem + boa);
            al[i] = *(const bf16x8*)(smem + 8192 + boa);
        }
#pragma unroll
        for (int j = 0; j < 3; ++j) {
            int rb = wn + j * 16 + c15;
            int bob = rb * 64 + ((g ^ (rb & 3)) << 4);
            bh[j] = *(const bf16x8*)(smem + 16384 + bob);
            bl[j] = *(const bf16x8*)(smem + 22528 + bob);
        }
        __builtin_amdgcn_s_setprio(1);
#pragma unroll
        for (int i = 0; i < 4; ++i)
#pragma unroll
            for (int j = 0; j < 3; ++j) {
                acc[i][j] = __builtin_amdgcn_mfma_f32_16x16x32_bf16(ah[i], bh[j], acc[i][j], 0, 0, 0);
                acc[i][j] = __builtin_amdgcn_mfma_f32_16x16x32_bf16(ah[i], bl[j], acc[i][j], 0, 0, 0);
                acc[i][j] = __builtin_amdgcn_mfma_f32_16x16x32_bf16(al[i], bh[j], acc[i][j], 0, 0, 0);
            }
        __builtin_amdgcn_s_setprio(0);
    }

    const int nq = n0 + wn;
    if (MODE == 0) {
#pragma unroll
        for (int j = 0; j < 3; ++j) {
            float bb = bias[nq + j * 16 + c15];
#pragma unroll
            for (int i = 0; i < 4; ++i)
#pragma unroll
                for (int r = 0; r < 4; ++r) {
                    int mm = m0 + wm + i * 16 + g * 4 + r;
                    Cout[(size_t)mm * N + nq + j * 16 + c15] = acc[i][j][r] + bb;
                }
        }
    } else {
        const int which = nq / 768;          // uniform per wave
        // q scaled by 0.125 * log2(e) so attention scores are in log2 units
        const float scale = (which == 0) ? 0.18033688f : 1.0f;
#pragma unroll
        for (int j = 0; j < 3; ++j) {
            int colg = nq + j * 16;
            int head = (colg % 768) >> 6;    // uniform per j
            int dbase = colg & 63;
            float bb = bias[colg + c15];
#pragma unroll
            for (int i = 0; i < 4; ++i)
#pragma unroll
                for (int r = 0; r < 4; ++r) {
                    int mm = m0 + wm + i * 16 + g * 4 + r;
                    float val = acc[i][j][r] + bb;
                    qkvbf[((size_t)(which * NH + head) * N_TOK + mm) * 64 + dbase + c15] =
                        f2b(val * scale);
                }
        }
    }
}

// ---------------------------------------------------------------------------
// rel_w precompute (rel_h fused into attn). q stored as q*0.125*log2e, so
// Qt = qbf * 8 = q * log2e  ->  rw = q . rpw * log2e  (log2 units). bf16 out.
// ---------------------------------------------------------------------------
__global__ __launch_bounds__(256)
void relpos_rw(const unsigned short* __restrict__ qkvbf,
               const float* __restrict__ rel_pos_w,
               unsigned short* __restrict__ rw) {
    const int qh = blockIdx.x;
    const int h  = blockIdx.y;
    const int t  = threadIdx.x, tx = t & 15, ty = t >> 4;
    const unsigned short* qbf = qkvbf + (size_t)h * N_TOK * 64;

    __shared__ float Qt[64][68];
    __shared__ float RW[127][68];

#pragma unroll
    for (int u = 0; u < 2; ++u) {
        int idx = u * 256 + t;
        int row = idx >> 3, ch = idx & 7;
        bf16x8 v = *(const bf16x8*)&qbf[(size_t)(qh * 64 + row) * 64 + ch * 8];
#pragma unroll
        for (int j = 0; j < 8; ++j)
            Qt[row][ch * 8 + j] = b2f((unsigned short)v[j]) * 8.0f;
    }
#pragma unroll
    for (int u = 0; u < 8; ++u) {
        int idx = u * 256 + t;
        if (idx < 127 * 16) {
            int row = idx >> 4, c4 = idx & 15;
            *(float4*)&RW[row][c4 * 4] =
                *(const float4*)&rel_pos_w[(size_t)row * HD + c4 * 4];
        }
    }
    __syncthreads();

    float acc2[4][4];
#pragma unroll
    for (int i = 0; i < 4; ++i)
#pragma unroll
        for (int j = 0; j < 4; ++j) acc2[i][j] = 0.f;

    for (int c4 = 0; c4 < 16; ++c4) {
        float4 q4[4];
#pragma unroll
        for (int i = 0; i < 4; ++i) q4[i] = *(float4*)&Qt[ty * 4 + i][c4 * 4];
#pragma unroll
        for (int i = 0; i < 4; ++i)
#pragma unroll
            for (int j = 0; j < 4; ++j) {
                float4 w4 = *(float4*)&RW[(ty * 4 + i) - (tx * 4 + j) + 63][c4 * 4];
                acc2[i][j] = fmaf(q4[i].x, w4.x, acc2[i][j]);
                acc2[i][j] = fmaf(q4[i].y, w4.y, acc2[i][j]);
                acc2[i][j] = fmaf(q4[i].z, w4.z, acc2[i][j]);
                acc2[i][j] = fmaf(q4[i].w, w4.w, acc2[i][j]);
            }
    }
#pragma unroll
    for (int i = 0; i < 4; ++i) {
        size_t base = ((size_t)h * N_TOK + qh * 64 + ty * 4 + i) * 64 + tx * 4;
        us4 w4;
        w4.x = f2b(acc2[i][0]); w4.y = f2b(acc2[i][1]);
        w4.z = f2b(acc2[i][2]); w4.w = f2b(acc2[i][3]);
        *(us4*)&rw[base] = w4;
    }
}

// ---------------------------------------------------------------------------
// Flash attention, bf16 MFMA, log2-domain softmax.
// R7: l accumulated via ones-column MFMA (acc[4], Vt rows 64..79);
//     m absorbed into rwm registers (z = s + rhv + rwm is exp2-ready);
//     rescale only when z_max > 11.5 (defer-max in log2 units).
// ---------------------------------------------------------------------------
__global__ __launch_bounds__(256, 3)
void attn_mfma(const unsigned short* __restrict__ qkvbf,
               const unsigned short* __restrict__ rw,
               const float* __restrict__ rel_pos_h,
               unsigned short* __restrict__ aohi, unsigned short* __restrict__ aolo) {
    int lin = blockIdx.y * 64 + blockIdx.x;       // 768 blocks
    lin = (lin & 7) * 96 + (lin >> 3);            // bijective XCD swizzle
    const int qt = lin & 63, h = lin >> 6;
    const int t = threadIdx.x;
    const int lane = t & 63, w = t >> 6;
    const int c15 = lane & 15, g = lane >> 4;

    const unsigned short* qbf = qkvbf + ((size_t)(0 * NH + h)) * N_TOK * 64;
    const unsigned short* kbf = qkvbf + ((size_t)(1 * NH + h)) * N_TOK * 64;
    const unsigned short* vbf = qkvbf + ((size_t)(2 * NH + h)) * N_TOK * 64;

    __shared__ __align__(16) unsigned short Qs[64 * 64];
    __shared__ __align__(16) unsigned short Ks[2][64 * 64];   // [1] hosts RH8 at init
    __shared__ __align__(16) unsigned short Vt[2][80 * 64];   // rows 64..79: ones block
    __shared__ __align__(16) unsigned short Ps[4][16 * 64];

    // ---- K/V register-stage helpers (T14)
    const int pi = t & 31;
    const int d0 = (t >> 5) * 8;
    const int vm = (pi & 15) + (pi >> 4) * 32;    // key pair (vm, vm+16)
    const int pbase = (pi & 15) * 4 + (pi >> 4) * 2;
    const int kr_row = t >> 3, kr_ch = t & 7;
    bf16x8 kr0, kr1, vr0, vr1;
    auto LOADKV = [&](int kt) {
        kr0 = *(const bf16x8*)&kbf[(size_t)(kt * 64 + kr_row) * 64 + kr_ch * 8];
        kr1 = *(const bf16x8*)&kbf[(size_t)(kt * 64 + 32 + kr_row) * 64 + kr_ch * 8];
        vr0 = *(const bf16x8*)&vbf[(size_t)(kt * 64 + vm) * 64 + d0];
        vr1 = *(const bf16x8*)&vbf[(size_t)(kt * 64 + vm + 16) * 64 + d0];
    };
    auto WRITEKV = [&](int buf) {
        int b0 = (kr_ch * 16) ^ ((kr_row & 7) << 4);
        *(bf16x8*)((char*)&Ks[buf][kr_row * 64] + b0) = kr0;
        int r1 = 32 + kr_row;
        int b1 = (kr_ch * 16) ^ ((r1 & 7) << 4);
        *(bf16x8*)((char*)&Ks[buf][r1 * 64] + b1) = kr1;
#pragma unroll
        for (int j = 0; j < 8; ++j) {
            int d = d0 + j;
            unsigned int pk = (unsigned int)(unsigned short)vr0[j]
                            | ((unsigned int)(unsigned short)vr1[j] << 16);
            int boff = (pbase * 2) ^ ((d & 7) << 4);
            *(unsigned int*)((char*)&Vt[buf][d * 64] + boff) = pk;
        }
    };

    // ---- init: stage Q; RH8 (=8*rel_pos_h, bf16) into Ks[1]; ones-block
#pragma unroll
    for (int u = 0; u < 2; ++u) {
        int idx = u * 256 + t;
        int row = idx >> 3, ch = idx & 7;
        bf16x8 v = *(const bf16x8*)&qbf[(size_t)(qt * 64 + row) * 64 + ch * 8];
        int boff = (ch * 16) ^ ((row & 7) << 4);
        *(bf16x8*)((char*)&Qs[row * 64] + boff) = v;
    }
#pragma unroll
    for (int u = 0; u < 4; ++u) {
        int idx = u * 256 + t;
        int row = idx >> 4, c4 = idx & 15;  // row = kt index
        float4 v = *(const float4*)&rel_pos_h[(size_t)(qt - row + 63) * HD + c4 * 4];
        us4 p = {f2b(v.x * 8.f), f2b(v.y * 8.f), f2b(v.z * 8.f), f2b(v.w * 8.f)};
        int boff = (c4 * 8) ^ ((row & 7) << 4);
        *(us4*)((char*)&Ks[1][row * 64] + boff) = p;
    }
    // ones block: Vt rows 64..79 (row 64 = 1.0, rest 0), both buffers
#pragma unroll
    for (int u = 0; u < 4; ++u) {
        int idx = u * 256 + t;              // 0..1023 = 16 rows x 64 pos
        int dr = 64 + (idx >> 6), pos = idx & 63;
        unsigned short val = (dr == 64) ? (unsigned short)0x3F80 : (unsigned short)0;
        int boff = (pos * 2) ^ ((dr & 7) << 4);
        *(unsigned short*)((char*)&Vt[0][dr * 64] + boff) = val;
        *(unsigned short*)((char*)&Vt[1][dr * 64] + boff) = val;
    }
    LOADKV(0);
    __syncthreads();

    WRITEKV(0);
    bf16x8 qf[2];
    {
        int row = w * 16 + c15;
#pragma unroll
        for (int ks = 0; ks < 2; ++ks) {
            int boff = (ks * 64 + g * 16) ^ ((row & 7) << 4);
            qf[ks] = *(bf16x8*)((char*)&Qs[row * 64] + boff);
        }
    }
    // rhacc[nt][r] = rh (log2 units) for q-row w*16+g*4+r, kt = nt*16 + c15
    f32x4 rhacc[4];
#pragma unroll
    for (int nt = 0; nt < 4; ++nt) {
        int krow = nt * 16 + c15;
        int b0 = (g * 16) ^ ((krow & 7) << 4);
        int b1 = (64 + g * 16) ^ ((krow & 7) << 4);
        bf16x8 rf0 = *(bf16x8*)((char*)&Ks[1][krow * 64] + b0);
        bf16x8 rf1 = *(bf16x8*)((char*)&Ks[1][krow * 64] + b1);
        f32x4 z = {0.f, 0.f, 0.f, 0.f};
        z = __builtin_amdgcn_mfma_f32_16x16x32_bf16(qf[0], rf0, z, 0, 0, 0);
        z = __builtin_amdgcn_mfma_f32_16x16x32_bf16(qf[1], rf1, z, 0, 0, 0);
        rhacc[nt] = z;
    }
    LOADKV(1);

    // rwm = rw - m  (m starts at 0). All log2 units.
    float rwm[4][4];
#pragma unroll
    for (int nt = 0; nt < 4; ++nt)
#pragma unroll
        for (int r = 0; r < 4; ++r)
            rwm[nt][r] = b2f(rw[((size_t)h * N_TOK + qt * 64 + w * 16 + g * 4 + r) * 64
                               + nt * 16 + c15]);

    f32x4 acc[5];   // [0..3]: O over d; [4]: ones-column (col 0 = l)
#pragma unroll
    for (int nt = 0; nt < 5; ++nt) acc[nt] = f32x4{0.f, 0.f, 0.f, 0.f};

    __syncthreads();   // Ks[0]/Vt[0] visible; rhacc reads of Ks[1] complete

#pragma unroll
    for (int kt4 = 0; kt4 < 4; ++kt4) {
#pragma unroll 2
        for (int kti = 0; kti < 16; ++kti) {
            const int kt = kt4 * 16 + kti;
            const int cur = kt & 1, nxt = cur ^ 1;
            if (kt < 63) WRITEKV(nxt);
            if (kt < 62) LOADKV(kt + 2);

            // ---- S = Q K^T (log2 units)
            f32x4 s[4];
            __builtin_amdgcn_s_setprio(1);
#pragma unroll
            for (int nt = 0; nt < 4; ++nt) {
                int krow = nt * 16 + c15;
                int b0 = (g * 16) ^ ((krow & 7) << 4);
                int b1 = (64 + g * 16) ^ ((krow & 7) << 4);
                bf16x8 kf0 = *(bf16x8*)((char*)&Ks[cur][krow * 64] + b0);
                bf16x8 kf1 = *(bf16x8*)((char*)&Ks[cur][krow * 64] + b1);
                f32x4 z = {0.f, 0.f, 0.f, 0.f};
                z = __builtin_amdgcn_mfma_f32_16x16x32_bf16(qf[0], kf0, z, 0, 0, 0);
                z = __builtin_amdgcn_mfma_f32_16x16x32_bf16(qf[1], kf1, z, 0, 0, 0);
                s[nt] = z;
            }
            __builtin_amdgcn_s_setprio(0);

            // ---- z = s + rh + (rw - m): exp2-ready
            float rhv[4];
#pragma unroll
            for (int r = 0; r < 4; ++r)
                rhv[r] = __shfl(rhacc[kt4][r], (lane & 48) | kti, 64);
#pragma unroll
            for (int nt = 0; nt < 4; ++nt)
#pragma unroll
                for (int r = 0; r < 4; ++r)
                    s[nt][r] += rhv[r] + rwm[nt][r];

            // ---- deferred rescale: only if z_max > 11.5 (= 8 nats)
            float mx[4];
#pragma unroll
            for (int r = 0; r < 4; ++r)
                mx[r] = fmaxf(fmaxf(s[0][r], s[1][r]), fmaxf(s[2][r], s[3][r]));
#pragma unroll
            for (int off = 1; off < 16; off <<= 1)
#pragma unroll
                for (int r = 0; r < 4; ++r)
                    mx[r] = fmaxf(mx[r], __shfl_xor(mx[r], off, 64));

            bool need = false;
#pragma unroll
            for (int r = 0; r < 4; ++r) need |= (mx[r] > 11.5f);
            if (__any(need ? 1 : 0)) {
#pragma unroll
                for (int r = 0; r < 4; ++r) {
                    float delta = fmaxf(mx[r], 0.f);
                    float corr = __builtin_amdgcn_exp2f(-delta);
#pragma unroll
                    for (int nt = 0; nt < 5; ++nt) acc[nt][r] *= corr;
#pragma unroll
                    for (int nt = 0; nt < 4; ++nt) {
                        rwm[nt][r] -= delta;
                        s[nt][r]   -= delta;
                    }
                }
            }
            // ---- P = exp2(z)
#pragma unroll
            for (int nt = 0; nt < 4; ++nt)
#pragma unroll
                for (int r = 0; r < 4; ++r)
                    s[nt][r] = __builtin_amdgcn_exp2f(s[nt][r]);

            // ---- P -> LDS (permuted pos = (key&15)*4 + key>>4)
#pragma unroll
            for (int r = 0; r < 4; ++r) {
                int row = g * 4 + r;
                int hr = (row ^ (row >> 1)) & 7;
                uint2 pv;
                pv.x = pk2(s[0][r], s[1][r]);
                pv.y = pk2(s[2][r], s[3][r]);
                int boff = (c15 * 8) ^ (hr << 4);
                *(uint2*)((char*)&Ps[w][row * 64] + boff) = pv;
            }

            // ---- O += P V ; l accumulates via ones-column (acc[4])
            const int hc = (c15 ^ (c15 >> 1)) & 7;
            __builtin_amdgcn_s_setprio(1);
#pragma unroll
            for (int ks = 0; ks < 2; ++ks) {
                int pb = (g * 32 + ks * 16) ^ (hc << 4);
                bf16x8 pf = *(bf16x8*)((char*)&Ps[w][c15 * 64] + pb);
#pragma unroll
                for (int nt = 0; nt < 4; ++nt) {
                    int drow = nt * 16 + c15;
                    int vb = (g * 32 + ks * 16) ^ ((drow & 7) << 4);
                    bf16x8 vf = *(bf16x8*)((char*)&Vt[cur][drow * 64] + vb);
                    acc[nt] = __builtin_amdgcn_mfma_f32_16x16x32_bf16(pf, vf, acc[nt], 0, 0, 0);
                }
                int drow5 = 64 + c15;
                int vb5 = (g * 32 + ks * 16) ^ ((drow5 & 7) << 4);
                bf16x8 vf5 = *(bf16x8*)((char*)&Vt[cur][drow5 * 64] + vb5);
                acc[4] = __builtin_amdgcn_mfma_f32_16x16x32_bf16(pf, vf5, acc[4], 0, 0, 0);
            }
            __builtin_amdgcn_s_setprio(0);

            __syncthreads();   // all waves done with buf[cur] before next overwrite
        }
    }

    // ---- epilogue: l = acc[4] col 0 (lane c15==0 of own g-group)
#pragma unroll
    for (int r = 0; r < 4; ++r) {
        float l = __shfl(acc[4][r], lane & 48, 64);
        float inv = 1.0f / l;
        size_t orow = (size_t)(qt * 64 + w * 16 + g * 4 + r) * 768 + h * HD;
#pragma unroll
        for (int nt = 0; nt < 4; ++nt) {
            float o = acc[nt][r] * inv;
            unsigned short hi = f2b(o);
            unsigned short lo = f2b(o - b2f(hi));
            aohi[orow + nt * 16 + c15] = hi;
            aolo[orow + nt * 16 + c15] = lo;
        }
    }
}

// ---------------------------------------------------------------------------
extern "C" void kernel_launch(void* const* d_in, const int* in_sizes, int n_in,
                              void* d_out, int out_size, void* d_ws, size_t ws_size,
                              hipStream_t stream) {
    const float* x      = (const float*)d_in[0];
    const float* w_qkv  = (const float*)d_in[1];
    const float* b_qkv  = (const float*)d_in[2];
    const float* w_proj = (const float*)d_in[3];
    const float* b_proj = (const float*)d_in[4];
    const float* rph    = (const float*)d_in[5];
    const float* rpw    = (const float*)d_in[6];
    float* out = (float*)d_out;

    char* p = (char*)d_ws;
    unsigned short* qkvbf = (unsigned short*)p; p += (size_t)3 * NH * N_TOK * 64 * 2;
    unsigned short* rwbf  = (unsigned short*)p; p += (size_t)NH * N_TOK * 64 * 2;
    unsigned short* xhi   = (unsigned short*)p; p += (size_t)N_TOK * 768 * 2;
    unsigned short* xlo   = (unsigned short*)p; p += (size_t)N_TOK * 768 * 2;
    unsigned short* wqThi = (unsigned short*)p; p += (size_t)2304 * 768 * 2;
    unsigned short* wqTlo = (unsigned short*)p; p += (size_t)2304 * 768 * 2;
    unsigned short* wpThi = (unsigned short*)p; p += (size_t)768 * 768 * 2;
    unsigned short* wpTlo = (unsigned short*)p; p += (size_t)768 * 768 * 2;
    unsigned short* aohi = xhi;   // alias: x consumed before attn writes ao
    unsigned short* aolo = xlo;

    conv_split<<<1024, 256, 0, stream>>>(x, xhi, xlo, N_TOK * 768 / 4);
    transpose_split<<<dim3(36, 12), 256, 0, stream>>>(w_qkv, wqThi, wqTlo, 768, 2304);
    transpose_split<<<dim3(12, 12), 256, 0, stream>>>(w_proj, wpThi, wpTlo, 768, 768);

    gemm_split<N_TOK, 2304, 768, 1><<<dim3(24, 32), 256, 0, stream>>>(
        xhi, xlo, wqThi, wqTlo, b_qkv, nullptr, qkvbf);

    relpos_rw<<<dim3(64, NH), 256, 0, stream>>>(qkvbf, rpw, rwbf);

    attn_mfma<<<dim3(64, NH), 256, 0, stream>>>(qkvbf, rwbf, rph, aohi, aolo);

    gemm_split<N_TOK, 768, 768, 0><<<dim3(8, 32), 256, 0, stream>>>(
        aohi, aolo, wpThi, wpTlo, b_proj, out, nullptr);
}

// Round 8
// 290.382 us; speedup vs baseline: 6.9091x; 1.0393x over previous
//
#include <hip/hip_runtime.h>
#include <math.h>

#define N_TOK 4096
#define DIM   768
#define NH    12
#define HD    64

typedef __attribute__((ext_vector_type(8))) short bf16x8;
typedef __attribute__((ext_vector_type(4))) float f32x4;
typedef __attribute__((ext_vector_type(4))) unsigned short us4;

__device__ inline unsigned short f2b(float f) {   // fp32 -> bf16 RNE
    union { float f; unsigned int u; } v; v.f = f;
    unsigned int r = v.u + 0x7FFFu + ((v.u >> 16) & 1u);
    return (unsigned short)(r >> 16);
}
__device__ inline float b2f(unsigned short u) {
    union { unsigned int u; float f; } v; v.u = ((unsigned int)u) << 16;
    return v.f;
}
__device__ inline unsigned int pk2(float lo, float hi) {   // 2x f32 -> packed bf16 RNE
    unsigned int u;
    asm("v_cvt_pk_bf16_f32 %0, %1, %2" : "=v"(u) : "v"(lo), "v"(hi));
    return u;
}
__device__ inline void gload16(const void* g, void* l) {
    __builtin_amdgcn_global_load_lds(
        (const __attribute__((address_space(1))) unsigned int*)g,
        (__attribute__((address_space(3))) unsigned int*)l, 16, 0, 0);
}

// ---------------------------------------------------------------------------
// fp32 -> (hi, lo) bf16 split, elementwise.  n4 = elems/4.
// ---------------------------------------------------------------------------
__global__ __launch_bounds__(256)
void conv_split(const float* __restrict__ X, unsigned short* __restrict__ hi,
                unsigned short* __restrict__ lo, int n4) {
    int i = blockIdx.x * 256 + threadIdx.x;
    int stride = gridDim.x * 256;
    for (; i < n4; i += stride) {
        float4 v = ((const float4*)X)[i];
        us4 h, l;
        h.x = f2b(v.x); l.x = f2b(v.x - b2f(h.x));
        h.y = f2b(v.y); l.y = f2b(v.y - b2f(h.y));
        h.z = f2b(v.z); l.z = f2b(v.z - b2f(h.z));
        h.w = f2b(v.w); l.w = f2b(v.w - b2f(h.w));
        ((us4*)hi)[i] = h;
        ((us4*)lo)[i] = l;
    }
}

// ---------------------------------------------------------------------------
// W[K][N] fp32 -> T[N][K] split bf16 (hi, lo). 64x64 tiles.
// ---------------------------------------------------------------------------
__global__ __launch_bounds__(256)
void transpose_split(const float* __restrict__ W, unsigned short* __restrict__ Thi,
                     unsigned short* __restrict__ Tlo, int K, int N) {
    __shared__ float tile[64][65];
    const int t = threadIdx.x;
    const int k0 = blockIdx.y * 64, n0 = blockIdx.x * 64;
#pragma unroll
    for (int u = 0; u < 4; ++u) {
        int idx = u * 256 + t;
        int r = idx >> 4, c4 = idx & 15;
        float4 v = *(const float4*)&W[(size_t)(k0 + r) * N + n0 + c4 * 4];
        tile[r][c4 * 4 + 0] = v.x; tile[r][c4 * 4 + 1] = v.y;
        tile[r][c4 * 4 + 2] = v.z; tile[r][c4 * 4 + 3] = v.w;
    }
    __syncthreads();
#pragma unroll
    for (int u = 0; u < 4; ++u) {
        int idx = u * 256 + t;
        int col = idx >> 4, c4 = idx & 15;
        float a0 = tile[c4 * 4 + 0][col], a1 = tile[c4 * 4 + 1][col];
        float a2 = tile[c4 * 4 + 2][col], a3 = tile[c4 * 4 + 3][col];
        us4 h, l;
        h.x = f2b(a0); l.x = f2b(a0 - b2f(h.x));
        h.y = f2b(a1); l.y = f2b(a1 - b2f(h.y));
        h.z = f2b(a2); l.z = f2b(a2 - b2f(h.z));
        h.w = f2b(a3); l.w = f2b(a3 - b2f(h.w));
        size_t o = (size_t)(n0 + col) * K + k0 + c4 * 4;
        *(us4*)&Thi[o] = h;
        *(us4*)&Tlo[o] = l;
    }
}

// ---------------------------------------------------------------------------
// Split-bf16 MFMA GEMM, BM=128 BN=96 BK=32. 4 waves, wave = 64x48.
// MODE 0: Cout[M][N] fp32 + bias.
// MODE 1: qkvbf[(which*NH+head)][tok][64] bf16, q pre-scaled 0.125*log2(e).
// ---------------------------------------------------------------------------
template<int M, int N, int K, int MODE>
__global__ __launch_bounds__(256)
void gemm_split(const unsigned short* __restrict__ Ahi, const unsigned short* __restrict__ Alo,
                const unsigned short* __restrict__ BThi, const unsigned short* __restrict__ BTlo,
                const float* __restrict__ bias, float* __restrict__ Cout,
                unsigned short* __restrict__ qkvbf) {
    __shared__ __align__(16) char smem[28672];   // Ahi 8K | Alo 8K | Bhi 6K | Blo 6K
    const int t = threadIdx.x, lane = t & 63, w = t >> 6;
    const int c15 = lane & 15, g = lane >> 4;
    const int nwg = gridDim.x * gridDim.y;
    int lin = blockIdx.y * gridDim.x + blockIdx.x;
    lin = (lin & 7) * (nwg >> 3) + (lin >> 3);   // bijective XCD swizzle (nwg%8==0)
    const int m0 = (lin / gridDim.x) * 128, n0 = (lin % gridDim.x) * 96;
    const int wm = (w >> 1) * 64, wn = (w & 1) * 48;

    f32x4 acc[4][3];
#pragma unroll
    for (int i = 0; i < 4; ++i)
#pragma unroll
        for (int j = 0; j < 3; ++j) acc[i][j] = f32x4{0.f, 0.f, 0.f, 0.f};

    for (int k0 = 0; k0 < K; k0 += 32) {
        __syncthreads();
#pragma unroll
        for (int p = 0; p < 2; ++p) {
            int off = p * 4096 + w * 1024 + lane * 16;
            int row = off >> 6;
            int gs  = ((off >> 4) & 3) ^ (row & 3);
            size_t ae = (size_t)(m0 + row) * K + k0 + gs * 8;
            char* dstA = smem + off - lane * 16;          // wave-uniform base
            gload16(Ahi + ae, dstA);
            gload16(Alo + ae, dstA + 8192);
            if (off < 6144) {                              // B: 96 rows only
                size_t be = (size_t)(n0 + row) * K + k0 + gs * 8;
                char* dstB = smem + 16384 + off - lane * 16;
                gload16(BThi + be, dstB);
                gload16(BTlo + be, dstB + 6144);
            }
        }
        __syncthreads();

        bf16x8 ah[4], al[4], bh[3], bl[3];
#pragma unroll
        for (int i = 0; i < 4; ++i) {
            int ra = wm + i * 16 + c15;
            int boa = ra * 64 + ((g ^ (ra & 3)) << 4);
            ah[i] = *(const bf16x8*)(smem + boa);
            al[i] = *(const bf16x8*)(smem + 8192 + boa);
        }
#pragma unroll
        for (int j = 0; j < 3; ++j) {
            int rb = wn + j * 16 + c15;
            int bob = rb * 64 + ((g ^ (rb & 3)) << 4);
            bh[j] = *(const bf16x8*)(smem + 16384 + bob);
            bl[j] = *(const bf16x8*)(smem + 22528 + bob);
        }
        __builtin_amdgcn_s_setprio(1);
#pragma unroll
        for (int i = 0; i < 4; ++i)
#pragma unroll
            for (int j = 0; j < 3; ++j) {
                acc[i][j] = __builtin_amdgcn_mfma_f32_16x16x32_bf16(ah[i], bh[j], acc[i][j], 0, 0, 0);
                acc[i][j] = __builtin_amdgcn_mfma_f32_16x16x32_bf16(ah[i], bl[j], acc[i][j], 0, 0, 0);
                acc[i][j] = __builtin_amdgcn_mfma_f32_16x16x32_bf16(al[i], bh[j], acc[i][j], 0, 0, 0);
            }
        __builtin_amdgcn_s_setprio(0);
    }

    const int nq = n0 + wn;
    if (MODE == 0) {
#pragma unroll
        for (int j = 0; j < 3; ++j) {
            float bb = bias[nq + j * 16 + c15];
#pragma unroll
            for (int i = 0; i < 4; ++i)
#pragma unroll
                for (int r = 0; r < 4; ++r) {
                    int mm = m0 + wm + i * 16 + g * 4 + r;
                    Cout[(size_t)mm * N + nq + j * 16 + c15] = acc[i][j][r] + bb;
                }
        }
    } else {
        const int which = nq / 768;          // uniform per wave
        const float scale = (which == 0) ? 0.18033688f : 1.0f;   // 0.125*log2(e)
#pragma unroll
        for (int j = 0; j < 3; ++j) {
            int colg = nq + j * 16;
            int head = (colg % 768) >> 6;    // uniform per j
            int dbase = colg & 63;
            float bb = bias[colg + c15];
#pragma unroll
            for (int i = 0; i < 4; ++i)
#pragma unroll
                for (int r = 0; r < 4; ++r) {
                    int mm = m0 + wm + i * 16 + g * 4 + r;
                    float val = acc[i][j][r] + bb;
                    qkvbf[((size_t)(which * NH + head) * N_TOK + mm) * 64 + dbase + c15] =
                        f2b(val * scale);
                }
        }
    }
}

// ---------------------------------------------------------------------------
// rel_w precompute. q stored as q*0.125*log2e -> Qt = qbf*8 = q*log2e,
// so rw is in log2 units. bf16 out, layout rw[h][tok][64 kw].
// ---------------------------------------------------------------------------
__global__ __launch_bounds__(256)
void relpos_rw(const unsigned short* __restrict__ qkvbf,
               const float* __restrict__ rel_pos_w,
               unsigned short* __restrict__ rw) {
    const int qh = blockIdx.x;
    const int h  = blockIdx.y;
    const int t  = threadIdx.x, tx = t & 15, ty = t >> 4;
    const unsigned short* qbf = qkvbf + (size_t)h * N_TOK * 64;

    __shared__ float Qt[64][68];
    __shared__ float RW[127][68];

#pragma unroll
    for (int u = 0; u < 2; ++u) {
        int idx = u * 256 + t;
        int row = idx >> 3, ch = idx & 7;
        bf16x8 v = *(const bf16x8*)&qbf[(size_t)(qh * 64 + row) * 64 + ch * 8];
#pragma unroll
        for (int j = 0; j < 8; ++j)
            Qt[row][ch * 8 + j] = b2f((unsigned short)v[j]) * 8.0f;
    }
#pragma unroll
    for (int u = 0; u < 8; ++u) {
        int idx = u * 256 + t;
        if (idx < 127 * 16) {
            int row = idx >> 4, c4 = idx & 15;
            *(float4*)&RW[row][c4 * 4] =
                *(const float4*)&rel_pos_w[(size_t)row * HD + c4 * 4];
        }
    }
    __syncthreads();

    float acc2[4][4];
#pragma unroll
    for (int i = 0; i < 4; ++i)
#pragma unroll
        for (int j = 0; j < 4; ++j) acc2[i][j] = 0.f;

    for (int c4 = 0; c4 < 16; ++c4) {
        float4 q4[4];
#pragma unroll
        for (int i = 0; i < 4; ++i) q4[i] = *(float4*)&Qt[ty * 4 + i][c4 * 4];
#pragma unroll
        for (int i = 0; i < 4; ++i)
#pragma unroll
            for (int j = 0; j < 4; ++j) {
                float4 w4 = *(float4*)&RW[(ty * 4 + i) - (tx * 4 + j) + 63][c4 * 4];
                acc2[i][j] = fmaf(q4[i].x, w4.x, acc2[i][j]);
                acc2[i][j] = fmaf(q4[i].y, w4.y, acc2[i][j]);
                acc2[i][j] = fmaf(q4[i].z, w4.z, acc2[i][j]);
                acc2[i][j] = fmaf(q4[i].w, w4.w, acc2[i][j]);
            }
    }
#pragma unroll
    for (int i = 0; i < 4; ++i) {
        size_t base = ((size_t)h * N_TOK + qh * 64 + ty * 4 + i) * 64 + tx * 4;
        us4 w4;
        w4.x = f2b(acc2[i][0]); w4.y = f2b(acc2[i][1]);
        w4.z = f2b(acc2[i][2]); w4.w = f2b(acc2[i][3]);
        *(us4*)&rw[base] = w4;
    }
}

// ---------------------------------------------------------------------------
// Flash attention, bf16 MFMA, log2-domain, SWAPPED operands (R8):
//   S^T = mfma(K, Q): lane holds 16 keys for q = w*16 + (lane&15).
//   P kept in registers; PV B-frags built via cvt_pk + shfl exchange.
//   l via constant ones A-fragment (no LDS ones block).
//   rh from RHs LDS table [kt][q] (built once via MFMA at init).
//   Epilogue: O^T -> LDS transpose (reuses Ks) -> coalesced global.
// ---------------------------------------------------------------------------
__global__ __launch_bounds__(256, 3)
void attn_mfma(const unsigned short* __restrict__ qkvbf,
               const unsigned short* __restrict__ rw,
               const float* __restrict__ rel_pos_h,
               unsigned short* __restrict__ aohi, unsigned short* __restrict__ aolo) {
    int lin = blockIdx.y * 64 + blockIdx.x;       // 768 blocks
    lin = (lin & 7) * 96 + (lin >> 3);            // bijective XCD swizzle
    const int qt = lin & 63, h = lin >> 6;
    const int t = threadIdx.x;
    const int lane = t & 63, w = t >> 6;
    const int c15 = lane & 15, g = lane >> 4;

    const unsigned short* qbf = qkvbf + ((size_t)(0 * NH + h)) * N_TOK * 64;
    const unsigned short* kbf = qkvbf + ((size_t)(1 * NH + h)) * N_TOK * 64;
    const unsigned short* vbf = qkvbf + ((size_t)(2 * NH + h)) * N_TOK * 64;

    __shared__ __align__(16) unsigned short Qs[64 * 64];       // init only
    __shared__ __align__(16) unsigned short Ks[2][64 * 64];    // [1] hosts RH8 at init
    __shared__ __align__(16) unsigned short Vt[2][64 * 64];    // [d][key]
    __shared__ __align__(16) unsigned short RHs[64 * 64];      // [kt][q] bf16

    // ---- K/V register staging (T14), natural key order
    const int pi = t & 31;
    const int d0 = (t >> 5) * 8;
    const int kr_row = t >> 3, kr_ch = t & 7;
    bf16x8 kr0, kr1, vr0, vr1;
    auto LOADKV = [&](int kt) {
        kr0 = *(const bf16x8*)&kbf[(size_t)(kt * 64 + kr_row) * 64 + kr_ch * 8];
        kr1 = *(const bf16x8*)&kbf[(size_t)(kt * 64 + 32 + kr_row) * 64 + kr_ch * 8];
        vr0 = *(const bf16x8*)&vbf[(size_t)(kt * 64 + pi * 2) * 64 + d0];
        vr1 = *(const bf16x8*)&vbf[(size_t)(kt * 64 + pi * 2 + 1) * 64 + d0];
    };
    auto WRITEKV = [&](int buf) {
        int b0 = (kr_ch * 16) ^ ((kr_row & 7) << 4);
        *(bf16x8*)((char*)&Ks[buf][kr_row * 64] + b0) = kr0;
        int r1 = 32 + kr_row;
        int b1 = (kr_ch * 16) ^ ((r1 & 7) << 4);
        *(bf16x8*)((char*)&Ks[buf][r1 * 64] + b1) = kr1;
#pragma unroll
        for (int j = 0; j < 8; ++j) {
            int d = d0 + j;
            unsigned int pk = (unsigned int)(unsigned short)vr0[j]
                            | ((unsigned int)(unsigned short)vr1[j] << 16);
            int boff = (pi * 4) ^ ((d & 7) << 4);
            *(unsigned int*)((char*)&Vt[buf][d * 64] + boff) = pk;
        }
    };

    // ---- init: stage Q; RH8 (=8*rel_pos_h, bf16) into Ks[1]
#pragma unroll
    for (int u = 0; u < 2; ++u) {
        int idx = u * 256 + t;
        int row = idx >> 3, ch = idx & 7;
        bf16x8 v = *(const bf16x8*)&qbf[(size_t)(qt * 64 + row) * 64 + ch * 8];
        int boff = (ch * 16) ^ ((row & 7) << 4);
        *(bf16x8*)((char*)&Qs[row * 64] + boff) = v;
    }
#pragma unroll
    for (int u = 0; u < 4; ++u) {
        int idx = u * 256 + t;
        int row = idx >> 4, c4 = idx & 15;  // row = kt index
        float4 v = *(const float4*)&rel_pos_h[(size_t)(qt - row + 63) * HD + c4 * 4];
        us4 p = {f2b(v.x * 8.f), f2b(v.y * 8.f), f2b(v.z * 8.f), f2b(v.w * 8.f)};
        int boff = (c4 * 8) ^ ((row & 7) << 4);
        *(us4*)((char*)&Ks[1][row * 64] + boff) = p;
    }
    LOADKV(0);
    __syncthreads();

    WRITEKV(0);
    // Q B-frags: col = q = w*16 + c15
    bf16x8 qf[2];
    {
        int row = w * 16 + c15;
#pragma unroll
        for (int ck = 0; ck < 2; ++ck) {
            int boff = (ck * 64 + g * 16) ^ ((row & 7) << 4);
            qf[ck] = *(bf16x8*)((char*)&Qs[row * 64] + boff);
        }
    }
    // rh^T[kt][q] via MFMA (A = RH8 rows=kt, B = Q^T): D col=q=c15, row=kt local
    {
#pragma unroll
        for (int nt = 0; nt < 4; ++nt) {
            int krow = nt * 16 + c15;
            int b0 = (g * 16) ^ ((krow & 7) << 4);
            int b1 = (64 + g * 16) ^ ((krow & 7) << 4);
            bf16x8 rf0 = *(bf16x8*)((char*)&Ks[1][krow * 64] + b0);
            bf16x8 rf1 = *(bf16x8*)((char*)&Ks[1][krow * 64] + b1);
            f32x4 z = {0.f, 0.f, 0.f, 0.f};
            z = __builtin_amdgcn_mfma_f32_16x16x32_bf16(rf0, qf[0], z, 0, 0, 0);
            z = __builtin_amdgcn_mfma_f32_16x16x32_bf16(rf1, qf[1], z, 0, 0, 0);
            // write to RHs[kt][q]: kt = nt*16 + g*4 + r, q = w*16 + c15
#pragma unroll
            for (int r = 0; r < 4; ++r)
                RHs[(nt * 16 + g * 4 + r) * 64 + w * 16 + c15] = f2b(z[r]);
        }
    }
    LOADKV(1);

    // rwm[nt][r] = rw - m for key j = nt*16+g*4+r, own q row. m starts 0.
    const int qrow = qt * 64 + w * 16 + c15;
    float rwm[4][4];
#pragma unroll
    for (int nt = 0; nt < 4; ++nt)
#pragma unroll
        for (int r = 0; r < 4; ++r)
            rwm[nt][r] = b2f(rw[((size_t)h * N_TOK + qrow) * 64 + nt * 16 + g * 4 + r]);

    f32x4 acc[4];    // O^T[d = nt*16+g*4+r][q = own]
    f32x4 acc5;      // ones-row: reg0 on g==0 lanes = l(q)
#pragma unroll
    for (int nt = 0; nt < 4; ++nt) acc[nt] = f32x4{0.f, 0.f, 0.f, 0.f};
    acc5 = f32x4{0.f, 0.f, 0.f, 0.f};

    // constant ones A-frag: row index = c15 -> only row 0 is ones
    union { unsigned int w4[4]; bf16x8 b; } onesu;
    {
        unsigned int ov = (c15 == 0) ? 0x3F803F80u : 0u;
        onesu.w4[0] = ov; onesu.w4[1] = ov; onesu.w4[2] = ov; onesu.w4[3] = ov;
    }
    const int srcE = ((g & 1) << 5) + c15;   // lane of G_even partner
    const int srcO = srcE + 16;              // lane of G_odd partner
    const bool hiSel = (g & 2) != 0;

    __syncthreads();   // Ks[0]/Vt[0]/RHs visible; Ks[1] reads done

#pragma unroll 2
    for (int kt = 0; kt < 64; ++kt) {
        const int cur = kt & 1, nxt = cur ^ 1;
        if (kt < 63) WRITEKV(nxt);
        if (kt < 62) LOADKV(kt + 2);

        // ---- S^T = K Q^T : lane holds keys nt*16+g*4+r for its q
        f32x4 s[4];
        __builtin_amdgcn_s_setprio(1);
#pragma unroll
        for (int nt = 0; nt < 4; ++nt) {
            int krow = nt * 16 + c15;
            int b0 = (g * 16) ^ ((krow & 7) << 4);
            int b1 = (64 + g * 16) ^ ((krow & 7) << 4);
            bf16x8 kf0 = *(bf16x8*)((char*)&Ks[cur][krow * 64] + b0);
            bf16x8 kf1 = *(bf16x8*)((char*)&Ks[cur][krow * 64] + b1);
            f32x4 z = {0.f, 0.f, 0.f, 0.f};
            z = __builtin_amdgcn_mfma_f32_16x16x32_bf16(kf0, qf[0], z, 0, 0, 0);
            z = __builtin_amdgcn_mfma_f32_16x16x32_bf16(kf1, qf[1], z, 0, 0, 0);
            s[nt] = z;
        }
        __builtin_amdgcn_s_setprio(0);

        // ---- z = s + rh + (rw - m)
        float rhv = b2f(RHs[kt * 64 + w * 16 + c15]);
#pragma unroll
        for (int nt = 0; nt < 4; ++nt)
#pragma unroll
            for (int r = 0; r < 4; ++r)
                s[nt][r] += rhv + rwm[nt][r];

        // ---- deferred rescale: local max only; full row-max in rare branch
        float mx = s[0][0];
#pragma unroll
        for (int nt = 0; nt < 4; ++nt)
#pragma unroll
            for (int r = 0; r < 4; ++r) mx = fmaxf(mx, s[nt][r]);
        if (__any(mx > 11.5f)) {
            float rm = fmaxf(mx, __shfl_xor(mx, 16, 64));
            rm = fmaxf(rm, __shfl_xor(rm, 32, 64));
            float delta = fmaxf(rm, 0.f);
            float corr = __builtin_amdgcn_exp2f(-delta);
#pragma unroll
            for (int nt = 0; nt < 4; ++nt) {
#pragma unroll
                for (int r = 0; r < 4; ++r) {
                    acc[nt][r] *= corr;
                    rwm[nt][r] -= delta;
                    s[nt][r]   -= delta;
                }
            }
#pragma unroll
            for (int r = 0; r < 4; ++r) acc5[r] *= corr;
        }
        // ---- P = exp2(z), pack to bf16 pairs
#pragma unroll
        for (int nt = 0; nt < 4; ++nt)
#pragma unroll
            for (int r = 0; r < 4; ++r)
                s[nt][r] = __builtin_amdgcn_exp2f(s[nt][r]);

        unsigned int u0[2], u1[2], u2[2], u3[2];   // u[nt][p], static names
        u0[0] = pk2(s[0][0], s[0][1]); u0[1] = pk2(s[0][2], s[0][3]);
        u1[0] = pk2(s[1][0], s[1][1]); u1[1] = pk2(s[1][2], s[1][3]);
        u2[0] = pk2(s[2][0], s[2][1]); u2[1] = pk2(s[2][2], s[2][3]);
        u3[0] = pk2(s[3][0], s[3][1]); u3[1] = pk2(s[3][2], s[3][3]);

        // ---- PV: B-frag (P^T) via shfl exchange; A = V^T from LDS
        __builtin_amdgcn_s_setprio(1);
#pragma unroll
        for (int ks = 0; ks < 2; ++ks) {
            unsigned int a0, a1;
            union { unsigned int w4[4]; bf16x8 b; } pu;
            if (ks == 0) {
                a0 = __shfl((int)u0[0], srcE); a1 = __shfl((int)u1[0], srcE);
                pu.w4[0] = hiSel ? a1 : a0;
                a0 = __shfl((int)u0[1], srcE); a1 = __shfl((int)u1[1], srcE);
                pu.w4[1] = hiSel ? a1 : a0;
                a0 = __shfl((int)u0[0], srcO); a1 = __shfl((int)u1[0], srcO);
                pu.w4[2] = hiSel ? a1 : a0;
                a0 = __shfl((int)u0[1], srcO); a1 = __shfl((int)u1[1], srcO);
                pu.w4[3] = hiSel ? a1 : a0;
            } else {
                a0 = __shfl((int)u2[0], srcE); a1 = __shfl((int)u3[0], srcE);
                pu.w4[0] = hiSel ? a1 : a0;
                a0 = __shfl((int)u2[1], srcE); a1 = __shfl((int)u3[1], srcE);
                pu.w4[1] = hiSel ? a1 : a0;
                a0 = __shfl((int)u2[0], srcO); a1 = __shfl((int)u3[0], srcO);
                pu.w4[2] = hiSel ? a1 : a0;
                a0 = __shfl((int)u2[1], srcO); a1 = __shfl((int)u3[1], srcO);
                pu.w4[3] = hiSel ? a1 : a0;
            }
            bf16x8 pf = pu.b;
#pragma unroll
            for (int nt = 0; nt < 4; ++nt) {
                int drow = nt * 16 + c15;
                int vb = (ks * 64 + g * 16) ^ ((drow & 7) << 4);
                bf16x8 vf = *(bf16x8*)((char*)&Vt[cur][drow * 64] + vb);
                acc[nt] = __builtin_amdgcn_mfma_f32_16x16x32_bf16(vf, pf, acc[nt], 0, 0, 0);
            }
            acc5 = __builtin_amdgcn_mfma_f32_16x16x32_bf16(onesu.b, pf, acc5, 0, 0, 0);
        }
        __builtin_amdgcn_s_setprio(0);

        __syncthreads();   // all waves done with buf[cur] before overwrite
    }

    // ---- epilogue: l from acc5 reg0 of g==0 lane; O^T -> LDS -> global
    float l = __shfl(acc5[0], c15, 64);    // lane c15 (g=0,r=0) holds l(q=c15)
    float inv = 1.0f / l;
    float* T = (float*)&Ks[0][0];          // [64 d][64 q] f32 (16 KB)
#pragma unroll
    for (int nt = 0; nt < 4; ++nt)
#pragma unroll
        for (int r = 0; r < 4; ++r)
            T[(nt * 16 + g * 4 + r) * 64 + w * 16 + c15] = acc[nt][r] * inv;
    __syncthreads();

    {
        int q = t >> 2, ck = t & 3;
        unsigned short hi[16], lo[16];
#pragma unroll
        for (int j = 0; j < 16; ++j) {
            float o = T[(ck * 16 + j) * 64 + q];
            hi[j] = f2b(o);
            lo[j] = f2b(o - b2f(hi[j]));
        }
        size_t go = (size_t)(qt * 64 + q) * 768 + h * HD + ck * 16;
        *(bf16x8*)&aohi[go]     = *(bf16x8*)&hi[0];
        *(bf16x8*)&aohi[go + 8] = *(bf16x8*)&hi[8];
        *(bf16x8*)&aolo[go]     = *(bf16x8*)&lo[0];
        *(bf16x8*)&aolo[go + 8] = *(bf16x8*)&lo[8];
    }
}

// ---------------------------------------------------------------------------
extern "C" void kernel_launch(void* const* d_in, const int* in_sizes, int n_in,
                              void* d_out, int out_size, void* d_ws, size_t ws_size,
                              hipStream_t stream) {
    const float* x      = (const float*)d_in[0];
    const float* w_qkv  = (const float*)d_in[1];
    const float* b_qkv  = (const float*)d_in[2];
    const float* w_proj = (const float*)d_in[3];
    const float* b_proj = (const float*)d_in[4];
    const float* rph    = (const float*)d_in[5];
    const float* rpw    = (const float*)d_in[6];
    float* out = (float*)d_out;

    char* p = (char*)d_ws;
    unsigned short* qkvbf = (unsigned short*)p; p += (size_t)3 * NH * N_TOK * 64 * 2;
    unsigned short* rwbf  = (unsigned short*)p; p += (size_t)NH * N_TOK * 64 * 2;
    unsigned short* xhi   = (unsigned short*)p; p += (size_t)N_TOK * 768 * 2;
    unsigned short* xlo   = (unsigned short*)p; p += (size_t)N_TOK * 768 * 2;
    unsigned short* wqThi = (unsigned short*)p; p += (size_t)2304 * 768 * 2;
    unsigned short* wqTlo = (unsigned short*)p; p += (size_t)2304 * 768 * 2;
    unsigned short* wpThi = (unsigned short*)p; p += (size_t)768 * 768 * 2;
    unsigned short* wpTlo = (unsigned short*)p; p += (size_t)768 * 768 * 2;
    unsigned short* aohi = xhi;   // alias: x consumed before attn writes ao
    unsigned short* aolo = xlo;

    conv_split<<<1024, 256, 0, stream>>>(x, xhi, xlo, N_TOK * 768 / 4);
    transpose_split<<<dim3(36, 12), 256, 0, stream>>>(w_qkv, wqThi, wqTlo, 768, 2304);
    transpose_split<<<dim3(12, 12), 256, 0, stream>>>(w_proj, wpThi, wpTlo, 768, 768);

    gemm_split<N_TOK, 2304, 768, 1><<<dim3(24, 32), 256, 0, stream>>>(
        xhi, xlo, wqThi, wqTlo, b_qkv, nullptr, qkvbf);

    relpos_rw<<<dim3(64, NH), 256, 0, stream>>>(qkvbf, rpw, rwbf);

    attn_mfma<<<dim3(64, NH), 256, 0, stream>>>(qkvbf, rwbf, rph, aohi, aolo);

    gemm_split<N_TOK, 768, 768, 0><<<dim3(8, 32), 256, 0, stream>>>(
        aohi, aolo, wpThi, wpTlo, b_proj, out, nullptr);
}